// Round 9
// baseline (508.231 us; speedup 1.0000x reference)
//
#include <hip/hip_runtime.h>
#include <stdint.h>

typedef short short8 __attribute__((ext_vector_type(8)));
typedef float floatx4 __attribute__((ext_vector_type(4)));
typedef unsigned short ushort_t;

constexpr int cFH = 11, cFW = 20, cP = 2784, cPM1 = 2783, cD = 704;
constexpr int cAFC = 64, cBBC = 512, cNB = 8, cNPAD = 2816, cM = 22272;
constexpr int cFTR = 768;   // featT padded rows

static __device__ __forceinline__ unsigned short f2bf(float f) {
  union { float f; unsigned u; } v; v.f = f;
  unsigned r = v.u + 0x7fffu + ((v.u >> 16) & 1u);
  return (unsigned short)(r >> 16);
}
static __device__ __forceinline__ int imin(int a, int b) { return a < b ? a : b; }

// bijective XCD-chunk swizzle (m204)
static __device__ __forceinline__ int xcd_swz(int orig, int total) {
  int q = total >> 3, r = total & 7;
  int xcd = orig & 7, pos = orig >> 3;
  return (xcd < r ? xcd * (q + 1) : r * (q + 1) + (xcd - r) * q) + pos;
}

// async global->LDS, 16B per lane, wave-uniform LDS base + lane*16
static __device__ __forceinline__ void gload16(const ushort_t* g, ushort_t* l) {
  __builtin_amdgcn_global_load_lds(
      (const __attribute__((address_space(1))) unsigned int*)g,
      (__attribute__((address_space(3))) unsigned int*)l, 16, 0, 0);
}

#define BARX() asm volatile("s_barrier" ::: "memory")
#define VMW2() asm volatile("s_waitcnt vmcnt(2)" ::: "memory")

// ---- 8-phase template building blocks (names bound to kernel locals) ----
#define G8_LOADA(RH, KH) do { \
  _Pragma("unroll") for (int rf_ = 0; rf_ < 4; ++rf_) \
    afr[rf_] = *(const short8*)(LA + offA[RH][KH][rf_]); } while (0)

#define G8_LOADB(KH) do { \
  _Pragma("unroll") for (int cf_ = 0; cf_ < 4; ++cf_) \
    bfr[cf_] = *(const short8*)(LB + offB[KH][cf_]); } while (0)

#define G8_MFMA(RH) do { \
  __builtin_amdgcn_s_setprio(1); \
  _Pragma("unroll") for (int rf_ = 0; rf_ < 4; ++rf_) \
    _Pragma("unroll") for (int cf_ = 0; cf_ < 4; ++cf_) \
      acc[(RH)*4+rf_][cf_] = __builtin_amdgcn_mfma_f32_16x16x32_bf16( \
          afr[rf_], bfr[cf_], acc[(RH)*4+rf_][cf_], 0, 0, 0); \
  __builtin_amdgcn_s_setprio(0); } while (0)

#define G8_STAGE(PTR, MAT, CHUNK) do { \
  gload16(PTR, &lds[ns][MAT][(CHUNK)*4096 + wid*512]); PTR += 64; } while (0)

// offsets: LDS tile [256 rows][64 cols] bf16; block-col swizzle blk ^= (row>>1)&7
#define G8_SETUP_OFFSETS() \
  int offA[2][2][4], offB[2][4]; \
  { int key = ((lr >> 1) & 7) << 3; \
    _Pragma("unroll") for (int rh_ = 0; rh_ < 2; ++rh_) \
      _Pragma("unroll") for (int kh_ = 0; kh_ < 2; ++kh_) \
        _Pragma("unroll") for (int rf_ = 0; rf_ < 4; ++rf_) { \
          int arow = wm * 128 + rh_ * 64 + rf_ * 16 + lr; \
          offA[rh_][kh_][rf_] = arow * 64 + ((((kh_ * 4 + lg) << 3)) ^ key); } \
    _Pragma("unroll") for (int kh_ = 0; kh_ < 2; ++kh_) \
      _Pragma("unroll") for (int cf_ = 0; cf_ < 4; ++cf_) { \
        int brow = wn * 64 + cf_ * 16 + lr; \
        offB[kh_][cf_] = brow * 64 + ((((kh_ * 4 + lg) << 3)) ^ key); } }

#define G8_PROLOGUE() do { int ns = 0; \
  G8_STAGE(pB0,1,0); G8_STAGE(pB1,1,1); G8_STAGE(pB2,1,2); G8_STAGE(pB3,1,3); \
  G8_STAGE(pA0,0,0); G8_STAGE(pA2,0,2); G8_STAGE(pA1,0,1); G8_STAGE(pA3,0,3); \
  VMW2(); BARX(); } while (0)

#define G8_KLOOP(NT) \
  for (int t = 0; t < (NT); ++t) { \
    int s_ = t & 1, ns = s_ ^ 1; \
    const ushort_t* LA = &lds[s_][0][0]; \
    const ushort_t* LB = &lds[s_][1][0]; \
    bool st = (t + 1 < (NT)); \
    short8 afr[4], bfr[4]; \
    /* P1: (rh0, kh0) */ \
    G8_LOADB(0); G8_LOADA(0, 0); \
    if (st) { G8_STAGE(pB0,1,0); G8_STAGE(pB1,1,1); } \
    BARX(); G8_MFMA(0); VMW2(); BARX(); \
    /* P2: (rh1, kh0) */ \
    G8_LOADA(1, 0); \
    if (st) { G8_STAGE(pB2,1,2); G8_STAGE(pB3,1,3); } \
    BARX(); G8_MFMA(1); BARX(); \
    /* P3: (rh0, kh1) */ \
    G8_LOADB(1); G8_LOADA(0, 1); \
    if (st) { G8_STAGE(pA0,0,0); G8_STAGE(pA2,0,2); } \
    BARX(); G8_MFMA(0); BARX(); \
    /* P4: (rh1, kh1) */ \
    G8_LOADA(1, 1); \
    if (st) { G8_STAGE(pA1,0,1); G8_STAGE(pA3,0,3); } \
    BARX(); G8_MFMA(1); VMW2(); BARX(); \
  }

// ---------------- 1x1 conv, 4 output channels per thread
__global__ void k_conv4(const float* __restrict__ x, const float* __restrict__ w,
                        const float* __restrict__ bias, float* __restrict__ f) {
  int idx = blockIdx.x * 256 + threadIdx.x;
  if (idx >= cNB * 16 * 220) return;
  int yx = idx % 220;
  int og = (idx / 220) % 16;
  int b  = idx / (220 * 16);
  int o0 = og * 4;
  const float* xp = x + (size_t)b * cBBC * 220 + yx;
  const float* w0 = w + (size_t)o0 * cBBC;
  const float* w1 = w0 + cBBC;
  const float* w2 = w1 + cBBC;
  const float* w3 = w2 + cBBC;
  float a0 = 0.f, a1 = 0.f, a2 = 0.f, a3 = 0.f;
#pragma unroll 4
  for (int c = 0; c < cBBC; ++c) {
    float xv = xp[(size_t)c * 220];
    a0 += xv * w0[c]; a1 += xv * w1[c]; a2 += xv * w2[c]; a3 += xv * w3[c];
  }
  f[((size_t)(b * cAFC + o0) * 220) + yx]     = a0 + bias[o0];
  f[((size_t)(b * cAFC + o0 + 1) * 220) + yx] = a1 + bias[o0 + 1];
  f[((size_t)(b * cAFC + o0 + 2) * 220) + yx] = a2 + bias[o0 + 2];
  f[((size_t)(b * cAFC + o0 + 3) * 220) + yx] = a3 + bias[o0 + 3];
}

// ---------------- gather -> feat bf16 [22272][704]
__global__ void k_gather8(const float* __restrict__ f, const int* __restrict__ cut_x,
                          const unsigned char* __restrict__ invalid,
                          ushort_t* __restrict__ feat) {
  int idx = blockIdx.x * 256 + threadIdx.x;
  if (idx >= cM * 88) return;
  int d8  = (idx % 88) * 8;
  int row = idx / 88;
  int p = row % cP;
  int b = row / cP;
  short8 v;
#pragma unroll
  for (int e = 0; e < 8; ++e) {
    int d = d8 + e;
    int o = d / cFH, i = d - o * cFH;
    int cx = cut_x[p * cFH + i];
    float vv = invalid[p * cFH + i] ? 0.f : f[((size_t)(b * cAFC + o) * cFH + i) * cFW + cx];
    v[e] = (short)f2bf(vv);
  }
  *(short8*)&feat[(size_t)row * cD + d8] = v;
}

// ---------------- feat -> featT bf16 [bz][768][2816]
__global__ void k_transpose(const ushort_t* __restrict__ feat,
                            ushort_t* __restrict__ featT, int b_base) {
  __shared__ ushort_t tile[64][66];
  int bz = blockIdx.z;
  int b  = b_base + bz;
  int p0 = blockIdx.x * 64, d0 = blockIdx.y * 64;
  int t = threadIdx.x;
#pragma unroll
  for (int m = 0; m < 16; ++m) {
    int idx = t + m * 256; int r = idx >> 6, c = idx & 63;
    int p = p0 + r;
    tile[r][c] = (p < cP) ? feat[((size_t)b * cP + p) * cD + d0 + c] : (ushort_t)0;
  }
  __syncthreads();
#pragma unroll
  for (int m = 0; m < 16; ++m) {
    int idx = t + m * 256; int r = idx >> 6, c = idx & 63;
    featT[((size_t)bz * cFTR + d0 + r) * cNPAD + p0 + c] = tile[c][r];
  }
}

// ---------------- att_w -> bf16 padded [2816][704]  +  Wt [80][1408]
__global__ void k_prep_w(const float* __restrict__ att_w, const float* __restrict__ reg_w,
                         const float* __restrict__ cls_w,
                         ushort_t* __restrict__ attw, ushort_t* __restrict__ Wt) {
  int idx = blockIdx.x * 256 + threadIdx.x;
  constexpr int n1 = cNPAD * cD;
  if (idx < n1) {
    int r = idx / cD;
    attw[idx] = (r < cPM1) ? f2bf(att_w[idx]) : (ushort_t)0;
  } else {
    int j = idx - n1;
    if (j < 80 * 1408) {
      int r = j / 1408, k = j % 1408;
      float v = 0.f;
      if (r < 73) v = reg_w[(size_t)r * 1408 + k];
      else if (r < 75) v = cls_w[(size_t)(r - 73) * 1408 + k];
      Wt[j] = f2bf(v);
    }
  }
}

// ---------------- denom[i] = sum of 44 partial slots; zero Pp diagonal
__global__ void k_denom(const float* __restrict__ partial, float* __restrict__ denom,
                        ushort_t* __restrict__ Pp, int n, int p_base) {
  int i = blockIdx.x * 256 + threadIdx.x;
  if (i >= n) return;
  float s = 0.f;
#pragma unroll 4
  for (int q = 0; q < 44; ++q) s += partial[(size_t)q * cM + i];
  denom[i] = s;
  Pp[(size_t)i * cNPAD + ((p_base + i) % cP)] = 0;
}

// ---------------- GEMM 1 (256^2 8-phase): S = feat @ attw^T; exp; scatter; partials
__global__ __launch_bounds__(512, 2) void k_gemm_s8(
    const ushort_t* __restrict__ feat, const ushort_t* __restrict__ attw,
    const float* __restrict__ att_b, ushort_t* __restrict__ Pp,
    float* __restrict__ partial, int m_base, int m_count, int pp_base) {
  __shared__ __align__(16) ushort_t lds[2][2][16384];
  int wg = xcd_swz(blockIdx.x, gridDim.x);
  int ntile = wg % 11, mtile = wg / 11;   // n fastest: A-panel shared on-XCD
  int tid = threadIdx.x;
  int wid = tid >> 6, lane = tid & 63, lr = lane & 15, lg = lane >> 4;
  int wm = wid >> 2, wn = wid & 3;
  int m0 = m_base + mtile * 256;
  int n0 = ntile * 256;
  int rmax = m_base + m_count - 1;

  G8_SETUP_OFFSETS();

  int srow = tid >> 3;
  int gcol = (((tid & 7) ^ ((srow >> 1) & 7)) << 3);
  const ushort_t* pA0 = feat + (size_t)imin(m0 +   0 + srow, rmax) * cD + gcol;
  const ushort_t* pA1 = feat + (size_t)imin(m0 +  64 + srow, rmax) * cD + gcol;
  const ushort_t* pA2 = feat + (size_t)imin(m0 + 128 + srow, rmax) * cD + gcol;
  const ushort_t* pA3 = feat + (size_t)imin(m0 + 192 + srow, rmax) * cD + gcol;
  const ushort_t* pB0 = attw + (size_t)(n0 +   0 + srow) * cD + gcol;
  const ushort_t* pB1 = attw + (size_t)(n0 +  64 + srow) * cD + gcol;
  const ushort_t* pB2 = attw + (size_t)(n0 + 128 + srow) * cD + gcol;
  const ushort_t* pB3 = attw + (size_t)(n0 + 192 + srow) * cD + gcol;

  floatx4 acc[8][4];
  floatx4 zero = {0.f, 0.f, 0.f, 0.f};
#pragma unroll
  for (int a = 0; a < 8; ++a)
#pragma unroll
    for (int q = 0; q < 4; ++q) acc[a][q] = zero;

  G8_PROLOGUE();
  G8_KLOOP(11);   // K = 704 = 11 tiles of 64

  // epilogue: exp, scatter store (diag skip), per-row partial sums
  float ab[4]; int kc[4];
#pragma unroll
  for (int n = 0; n < 4; ++n) {
    int k = n0 + wn * 64 + n * 16 + lr;
    kc[n] = k;
    ab[n] = (k < cPM1) ? att_b[k] : 0.f;
  }
#pragma unroll
  for (int m = 0; m < 8; ++m) {
#pragma unroll
    for (int r = 0; r < 4; ++r) {
      int i = m0 + wm * 128 + m * 16 + lg * 4 + r;
      bool rowok = (unsigned)(i - m_base) < (unsigned)m_count;
      int il = i - pp_base;
      int pl = i % cP;
      float ssum = 0.f;
#pragma unroll
      for (int n = 0; n < 4; ++n) {
        int k = kc[n];
        if (k < cPM1) {
          float e = __expf(acc[m][n][r] + ab[n]);
          ssum += e;
          if (rowok) Pp[(size_t)il * cNPAD + k + (k >= pl ? 1 : 0)] = f2bf(e);
        } else if (k <= cNPAD - 2) {
          if (rowok) Pp[(size_t)il * cNPAD + k + 1] = 0;
        }
      }
      ssum += __shfl_xor(ssum, 1); ssum += __shfl_xor(ssum, 2);
      ssum += __shfl_xor(ssum, 4); ssum += __shfl_xor(ssum, 8);
      if (lr == 0 && rowok)
        partial[(size_t)(ntile * 4 + wn) * cM + il] = ssum;
    }
  }
}

// ---------------- GEMM 2 (256^2 8-phase): att_feat = (Pp @ featT^T) / denom
__global__ __launch_bounds__(512, 2) void k_gemm_pv8(
    const ushort_t* __restrict__ Pp, const ushort_t* __restrict__ featT,
    const float* __restrict__ denom, ushort_t* __restrict__ af,
    int b_base, int pp_base, int ft_base, int af_base) {
  __shared__ __align__(16) ushort_t lds[2][2][16384];
  int wg = xcd_swz(blockIdx.x, gridDim.x);
  int ntile = wg % 3;
  int mtile = (wg / 3) % 11;
  int b = b_base + wg / 33;
  int tid = threadIdx.x;
  int wid = tid >> 6, lane = tid & 63, lr = lane & 15, lg = lane >> 4;
  int wm = wid >> 2, wn = wid & 3;
  int m0l = mtile * 256;
  int n0 = ntile * 256;
  int bP = b * cP - pp_base;

  G8_SETUP_OFFSETS();

  int srow = tid >> 3;
  int gcol = (((tid & 7) ^ ((srow >> 1) & 7)) << 3);
  const ushort_t* fb = featT + (size_t)(b - ft_base) * cFTR * cNPAD;
  const ushort_t* pA0 = Pp + (size_t)(bP + imin(m0l +   0 + srow, cP - 1)) * cNPAD + gcol;
  const ushort_t* pA1 = Pp + (size_t)(bP + imin(m0l +  64 + srow, cP - 1)) * cNPAD + gcol;
  const ushort_t* pA2 = Pp + (size_t)(bP + imin(m0l + 128 + srow, cP - 1)) * cNPAD + gcol;
  const ushort_t* pA3 = Pp + (size_t)(bP + imin(m0l + 192 + srow, cP - 1)) * cNPAD + gcol;
  const ushort_t* pB0 = fb + (size_t)(n0 +   0 + srow) * cNPAD + gcol;
  const ushort_t* pB1 = fb + (size_t)(n0 +  64 + srow) * cNPAD + gcol;
  const ushort_t* pB2 = fb + (size_t)(n0 + 128 + srow) * cNPAD + gcol;
  const ushort_t* pB3 = fb + (size_t)(n0 + 192 + srow) * cNPAD + gcol;

  floatx4 acc[8][4];
  floatx4 zero = {0.f, 0.f, 0.f, 0.f};
#pragma unroll
  for (int a = 0; a < 8; ++a)
#pragma unroll
    for (int q = 0; q < 4; ++q) acc[a][q] = zero;

  G8_PROLOGUE();
  G8_KLOOP(44);   // K = 2816 = 44 tiles of 64

#pragma unroll
  for (int m = 0; m < 8; ++m) {
#pragma unroll
    for (int r = 0; r < 4; ++r) {
      int p = m0l + wm * 128 + m * 16 + lg * 4 + r;
      if (p >= cP) continue;
      float rdn = __builtin_amdgcn_rcpf(denom[bP + p]);
#pragma unroll
      for (int n = 0; n < 4; ++n) {
        int dd = n0 + wn * 64 + n * 16 + lr;
        if (dd < cD)
          af[((size_t)(b * cP + p) - af_base) * cD + dd] = f2bf(acc[m][n][r] * rdn);
      }
    }
  }
}

// ---------------- GEMM 3 (staged A): [att_feat|feat] @ Wt^T + epilogue
__global__ __launch_bounds__(256, 4) void k_gemm_out(
    const ushort_t* __restrict__ af, const ushort_t* __restrict__ feat,
    const ushort_t* __restrict__ Wt,
    const float* __restrict__ reg_b, const float* __restrict__ cls_b,
    const float* __restrict__ anchors,
    float* __restrict__ out0, float* __restrict__ out1,
    float* __restrict__ out2, float* __restrict__ out3,
    int m_base, int m_count, int af_base) {
  __shared__ __align__(16) ushort_t sA[2][128 * 32];
  int tid = threadIdx.x;
  int w = tid >> 6, l = tid & 63, lr = l & 15, lg = l >> 4;
  int wr = w * 32;
  int m0 = m_base + blockIdx.x * 128;
  int lastRow = m_base + m_count - 1;

  int srow = w * 16 + (l >> 2), scol = (l & 3) * 8;
  const ushort_t* pa0_af = af + (size_t)(imin(m0 + srow, lastRow) - af_base) * cD + scol;
  const ushort_t* pa1_af = af + (size_t)(imin(m0 + 64 + srow, lastRow) - af_base) * cD + scol;
  const ushort_t* pa0_f  = feat + (size_t)imin(m0 + srow, lastRow) * cD + scol;
  const ushort_t* pa1_f  = feat + (size_t)imin(m0 + 64 + srow, lastRow) * cD + scol;
  int lbase = w * 512;

  floatx4 zero = {0.f, 0.f, 0.f, 0.f};
  floatx4 acc[2][5];
#pragma unroll
  for (int a = 0; a < 2; ++a)
#pragma unroll
    for (int q = 0; q < 5; ++q) acc[a][q] = zero;

  auto stageA = [&](int buf, int kk) {
    const ushort_t *s0, *s1;
    if (kk < 22) { s0 = pa0_af + kk * 32; s1 = pa1_af + kk * 32; }
    else         { s0 = pa0_f + (kk - 22) * 32; s1 = pa1_f + (kk - 22) * 32; }
    gload16(s0, &sA[buf][lbase]);
    gload16(s1, &sA[buf][lbase + 2048]);
  };

  stageA(0, 0);
  __syncthreads();
  int cur = 0;
  for (int kk = 0; kk < 44; ++kk) {
    if (kk + 1 < 44) stageA(cur ^ 1, kk + 1);
    int kb = kk * 32 + lg * 8;
    short8 avv[2];
#pragma unroll
    for (int mt = 0; mt < 2; ++mt)
      avv[mt] = *(const short8*)&sA[cur][(wr + mt * 16 + lr) * 32 + lg * 8];
#pragma unroll
    for (int nt = 0; nt < 5; ++nt) {
      short8 bvv = *(const short8*)(Wt + (size_t)(nt * 16 + lr) * 1408 + kb);
#pragma unroll
      for (int mt = 0; mt < 2; ++mt)
        acc[mt][nt] = __builtin_amdgcn_mfma_f32_16x16x32_bf16(avv[mt], bvv, acc[mt][nt], 0, 0, 0);
    }
    __syncthreads();
    cur ^= 1;
  }

#pragma unroll
  for (int mt = 0; mt < 2; ++mt)
#pragma unroll
    for (int nt = 0; nt < 5; ++nt)
#pragma unroll
      for (int r = 0; r < 4; ++r) {
        int i = m0 + wr + mt * 16 + lg * 4 + r;
        if (i - m_base >= m_count) continue;
        int o = nt * 16 + lr;
        int p = i % cP;
        float v = acc[mt][nt][r];
        const float* an = anchors + (size_t)p * 74;
        if (o == 0)        { out2[i] = an[1] + v + reg_b[0]; out1[i] = an[0]; }
        else if (o < 73)   { out0[(size_t)i * 72 + (o - 1)] = an[1 + o] + v + reg_b[o]; }
        else if (o == 73)  { out3[(size_t)i * 2]     = v + cls_b[0]; }
        else if (o == 74)  { out3[(size_t)i * 2 + 1] = v + cls_b[1]; }
      }
}

extern "C" void kernel_launch(void* const* d_in, const int* in_sizes, int n_in,
                              void* d_out, int out_size, void* d_ws, size_t ws_size,
                              hipStream_t stream) {
  const float* x       = (const float*)d_in[0];
  const float* conv_w  = (const float*)d_in[1];
  const float* conv_b  = (const float*)d_in[2];
  const float* att_w   = (const float*)d_in[3];
  const float* att_b   = (const float*)d_in[4];
  const float* cls_w   = (const float*)d_in[5];
  const float* cls_b   = (const float*)d_in[6];
  const float* reg_w   = (const float*)d_in[7];
  const float* reg_b   = (const float*)d_in[8];
  const float* anchors = (const float*)d_in[9];
  const int*   cut_x   = (const int*)d_in[10];
  const unsigned char* invalid = (const unsigned char*)d_in[11];
  float* out0 = (float*)d_out;
  float* out1 = out0 + (size_t)cM * 72;
  float* out2 = out1 + cM;
  float* out3 = out2 + cM;

  size_t off = 0;
  char* base = (char*)d_ws;
  auto carve = [&](size_t bytes) -> void* {
    void* r = base + off; off += (bytes + 255) & ~(size_t)255; return r;
  };
  float* fbuf            = (float*)carve((size_t)cNB * cAFC * cFH * cFW * 4);
  ushort_t* feat         = (ushort_t*)carve((size_t)cM * cD * 2);
  ushort_t* attw         = (ushort_t*)carve((size_t)cNPAD * cD * 2);
  ushort_t* Wt           = (ushort_t*)carve((size_t)80 * 1408 * 2);
  float* partial         = (float*)carve((size_t)44 * cM * 4);
  float* denom           = (float*)carve((size_t)cM * 4);

  size_t featT_full = (size_t)cNB * cFTR * cNPAD * 2, featT_one = (size_t)cFTR * cNPAD * 2;
  size_t af_full    = (size_t)cM * cD * 2,            af_one    = (size_t)cP * cD * 2;
  size_t pp_full    = (size_t)cM * cNPAD * 2,         pp_one    = (size_t)cNPAD * cNPAD * 2;

  size_t needA = off + featT_full + af_full + pp_full;
  size_t needB = off + featT_full + af_full + pp_one;
  int mode = (ws_size >= needA) ? 0 : ((ws_size >= needB) ? 1 : 2);

  ushort_t *featT, *af, *Pp;
  if (mode == 0)      { featT = (ushort_t*)carve(featT_full); af = (ushort_t*)carve(af_full); Pp = (ushort_t*)carve(pp_full); }
  else if (mode == 1) { featT = (ushort_t*)carve(featT_full); af = (ushort_t*)carve(af_full); Pp = (ushort_t*)carve(pp_one); }
  else                { featT = (ushort_t*)carve(featT_one);  af = (ushort_t*)carve(af_one);  Pp = (ushort_t*)carve(pp_one); }

  k_conv4<<<(cNB * 16 * 220 + 255) / 256, 256, 0, stream>>>(x, conv_w, conv_b, fbuf);
  k_gather8<<<(cM * 88 + 255) / 256, 256, 0, stream>>>(fbuf, cut_x, invalid, feat);
  k_prep_w<<<(cNPAD * cD + 80 * 1408 + 255) / 256, 256, 0, stream>>>(att_w, reg_w, cls_w, attw, Wt);

  if (mode == 0) {
    k_transpose<<<dim3(44, 11, 8), 256, 0, stream>>>(feat, featT, 0);
    k_gemm_s8<<<87 * 11, 512, 0, stream>>>(feat, attw, att_b, Pp, partial, 0, cM, 0);
    k_denom<<<(cM + 255) / 256, 256, 0, stream>>>(partial, denom, Pp, cM, 0);
    k_gemm_pv8<<<8 * 11 * 3, 512, 0, stream>>>(Pp, featT, denom, af, 0, 0, 0, 0);
    k_gemm_out<<<174, 256, 0, stream>>>(af, feat, Wt, reg_b, cls_b, anchors,
                                        out0, out1, out2, out3, 0, cM, 0);
  } else if (mode == 1) {
    k_transpose<<<dim3(44, 11, 8), 256, 0, stream>>>(feat, featT, 0);
    for (int b = 0; b < cNB; ++b) {
      k_gemm_s8<<<11 * 11, 512, 0, stream>>>(feat, attw, att_b, Pp, partial, b * cP, cP, b * cP);
      k_denom<<<(cP + 255) / 256, 256, 0, stream>>>(partial, denom, Pp, cP, b * cP);
      k_gemm_pv8<<<11 * 3, 512, 0, stream>>>(Pp, featT, denom, af, b, b * cP, 0, 0);
    }
    k_gemm_out<<<174, 256, 0, stream>>>(af, feat, Wt, reg_b, cls_b, anchors,
                                        out0, out1, out2, out3, 0, cM, 0);
  } else {
    for (int b = 0; b < cNB; ++b) {
      k_transpose<<<dim3(44, 11, 1), 256, 0, stream>>>(feat, featT, b);
      k_gemm_s8<<<11 * 11, 512, 0, stream>>>(feat, attw, att_b, Pp, partial, b * cP, cP, b * cP);
      k_denom<<<(cP + 255) / 256, 256, 0, stream>>>(partial, denom, Pp, cP, b * cP);
      k_gemm_pv8<<<11 * 3, 512, 0, stream>>>(Pp, featT, denom, af, b, b * cP, b, b * cP);
      k_gemm_out<<<22, 256, 0, stream>>>(af, feat, Wt, reg_b, cls_b, anchors,
                                         out0, out1, out2, out3, b * cP, cP, b * cP);
    }
  }
}

// Round 10
// 476.749 us; speedup vs baseline: 1.0660x; 1.0660x over previous
//
#include <hip/hip_runtime.h>
#include <stdint.h>

typedef short short8 __attribute__((ext_vector_type(8)));
typedef float floatx4 __attribute__((ext_vector_type(4)));
typedef unsigned short ushort_t;

constexpr int cFH = 11, cFW = 20, cP = 2784, cPM1 = 2783, cD = 704;
constexpr int cAFC = 64, cBBC = 512, cNB = 8, cNPAD = 2816, cM = 22272;
constexpr int cFTR = 768;   // featT padded rows

static __device__ __forceinline__ unsigned short f2bf(float f) {
  union { float f; unsigned u; } v; v.f = f;
  unsigned r = v.u + 0x7fffu + ((v.u >> 16) & 1u);
  return (unsigned short)(r >> 16);
}
static __device__ __forceinline__ int imin(int a, int b) { return a < b ? a : b; }
// LDS XOR swizzle: position (row, pcol) holds global col pcol ^ swz8(row)
static __device__ __forceinline__ int swz8(int row) { return ((row >> 1) & 3) << 3; }

// bijective XCD-chunk swizzle (m204)
static __device__ __forceinline__ int xcd_swz(int orig, int total) {
  int q = total >> 3, r = total & 7;
  int xcd = orig & 7, pos = orig >> 3;
  return (xcd < r ? xcd * (q + 1) : r * (q + 1) + (xcd - r) * q) + pos;
}

// async global->LDS, 16B per lane, wave-uniform LDS base + lane*16
static __device__ __forceinline__ void gload16(const ushort_t* g, ushort_t* l) {
  __builtin_amdgcn_global_load_lds(
      (const __attribute__((address_space(1))) unsigned int*)g,
      (__attribute__((address_space(3))) unsigned int*)l, 16, 0, 0);
}

#define PIPE_BAR4() asm volatile("s_waitcnt vmcnt(4)\n\ts_barrier" ::: "memory")
#define PIPE_BAR0() asm volatile("s_waitcnt vmcnt(0)\n\ts_barrier" ::: "memory")

// ---------------- 1x1 conv, 4 output channels per thread
__global__ void k_conv4(const float* __restrict__ x, const float* __restrict__ w,
                        const float* __restrict__ bias, float* __restrict__ f) {
  int idx = blockIdx.x * 256 + threadIdx.x;
  if (idx >= cNB * 16 * 220) return;
  int yx = idx % 220;
  int og = (idx / 220) % 16;
  int b  = idx / (220 * 16);
  int o0 = og * 4;
  const float* xp = x + (size_t)b * cBBC * 220 + yx;
  const float* w0 = w + (size_t)o0 * cBBC;
  const float* w1 = w0 + cBBC;
  const float* w2 = w1 + cBBC;
  const float* w3 = w2 + cBBC;
  float a0 = 0.f, a1 = 0.f, a2 = 0.f, a3 = 0.f;
#pragma unroll 4
  for (int c = 0; c < cBBC; ++c) {
    float xv = xp[(size_t)c * 220];
    a0 += xv * w0[c]; a1 += xv * w1[c]; a2 += xv * w2[c]; a3 += xv * w3[c];
  }
  f[((size_t)(b * cAFC + o0) * 220) + yx]     = a0 + bias[o0];
  f[((size_t)(b * cAFC + o0 + 1) * 220) + yx] = a1 + bias[o0 + 1];
  f[((size_t)(b * cAFC + o0 + 2) * 220) + yx] = a2 + bias[o0 + 2];
  f[((size_t)(b * cAFC + o0 + 3) * 220) + yx] = a3 + bias[o0 + 3];
}

// ---------------- fused gather + transpose: writes feat [22272][704] AND featT [bz][768][2816]
__global__ void k_gatherT(const float* __restrict__ f, const int* __restrict__ cut_x,
                          const unsigned char* __restrict__ invalid,
                          ushort_t* __restrict__ feat, ushort_t* __restrict__ featT,
                          int b_base) {
  __shared__ ushort_t tile[64][66];
  int bz = blockIdx.z;
  int b  = b_base + bz;
  int p0 = blockIdx.x * 64, d0 = blockIdx.y * 64;
  int t = threadIdx.x;
#pragma unroll
  for (int m = 0; m < 16; ++m) {
    int idx = t + m * 256; int r = idx >> 6, c = idx & 63;
    int p = p0 + r, d = d0 + c;
    ushort_t v = 0;
    if (p < cP) {
      int o = d / cFH, i2 = d - o * cFH;
      int cx = cut_x[p * cFH + i2];
      float vv = invalid[p * cFH + i2] ? 0.f
               : f[((size_t)(b * cAFC + o) * cFH + i2) * cFW + cx];
      v = f2bf(vv);
      feat[((size_t)b * cP + p) * cD + d] = v;
    }
    tile[r][c] = v;
  }
  __syncthreads();
#pragma unroll
  for (int m = 0; m < 16; ++m) {
    int idx = t + m * 256; int r = idx >> 6, c = idx & 63;
    featT[((size_t)bz * cFTR + d0 + r) * cNPAD + p0 + c] = tile[c][r];
  }
}

// ---------------- att_w -> bf16 padded [2816][704]  +  Wt [80][1408]
__global__ void k_prep_w(const float* __restrict__ att_w, const float* __restrict__ reg_w,
                         const float* __restrict__ cls_w,
                         ushort_t* __restrict__ attw, ushort_t* __restrict__ Wt) {
  int idx = blockIdx.x * 256 + threadIdx.x;
  constexpr int n1 = cNPAD * cD;
  if (idx < n1) {
    int r = idx / cD;
    attw[idx] = (r < cPM1) ? f2bf(att_w[idx]) : (ushort_t)0;
  } else {
    int j = idx - n1;
    if (j < 80 * 1408) {
      int r = j / 1408, k = j % 1408;
      float v = 0.f;
      if (r < 73) v = reg_w[(size_t)r * 1408 + k];
      else if (r < 75) v = cls_w[(size_t)(r - 73) * 1408 + k];
      Wt[j] = f2bf(v);
    }
  }
}

// ---------------- GEMM 1 (3-buf pipelined): S = feat @ attw^T; exp; scatter+diag; partials
__global__ __launch_bounds__(256, 4) void k_gemm_s2(
    const ushort_t* __restrict__ feat, const ushort_t* __restrict__ attw,
    const float* __restrict__ att_b, ushort_t* __restrict__ Pp,
    float* __restrict__ partial, int m_base, int m_count, int pp_base) {
  __shared__ __align__(16) ushort_t lds[3][8192];
  int wg = xcd_swz(blockIdx.x, gridDim.x);
  int ntile = wg % 22, mtile = wg / 22;
  int tid = threadIdx.x;
  int w = tid >> 6, l = tid & 63, lr = l & 15, lg = l >> 4;
  int wr = (w >> 1) * 64, wc = (w & 1) * 64;
  int m0 = m_base + mtile * 128;
  int n0 = ntile * 128;
  int rmaxA = m_base + m_count - 1;

  int srow = w * 16 + (l >> 2);
  int scol = ((l & 3) * 8) ^ swz8(srow);   // pre-swizzled global source col
  const ushort_t* a0 = feat + (size_t)imin(m0 + srow, rmaxA) * cD + scol;
  const ushort_t* a1 = feat + (size_t)imin(m0 + 64 + srow, rmaxA) * cD + scol;
  const ushort_t* b0 = attw + (size_t)(n0 + srow) * cD + scol;
  const ushort_t* b1 = attw + (size_t)(n0 + 64 + srow) * cD + scol;
  int w512 = w * 512;

  int offA[4], offB[4];
#pragma unroll
  for (int mt = 0; mt < 4; ++mt) {
    int row = wr + mt * 16 + lr;
    offA[mt] = row * 32 + ((lg * 8) ^ swz8(row));
  }
#pragma unroll
  for (int nt = 0; nt < 4; ++nt) {
    int row = wc + nt * 16 + lr;
    offB[nt] = 4096 + row * 32 + ((lg * 8) ^ swz8(row));
  }

  floatx4 acc[4][4];
  floatx4 zero = {0.f, 0.f, 0.f, 0.f};
#pragma unroll
  for (int a = 0; a < 4; ++a)
#pragma unroll
    for (int q = 0; q < 4; ++q) acc[a][q] = zero;

  auto stage = [&](int buf) {
    ushort_t* L = &lds[buf][w512];
    gload16(a0, L); gload16(a1, L + 2048);
    gload16(b0, L + 4096); gload16(b1, L + 6144);
    a0 += 32; a1 += 32; b0 += 32; b1 += 32;
  };

  stage(0); stage(1);
  int c0 = 0, c1 = 1, c2 = 2;
  constexpr int NK = cD / 32;  // 22
  for (int t = 0; t < NK; ++t) {
    if (t + 1 < NK) PIPE_BAR4(); else PIPE_BAR0();
    if (t + 2 < NK) stage(c2);
    const ushort_t* Lc = lds[c0];
    short8 av[4], bv[4];
#pragma unroll
    for (int mt = 0; mt < 4; ++mt) av[mt] = *(const short8*)(Lc + offA[mt]);
#pragma unroll
    for (int nt = 0; nt < 4; ++nt) bv[nt] = *(const short8*)(Lc + offB[nt]);
#pragma unroll
    for (int mt = 0; mt < 4; ++mt)
#pragma unroll
      for (int nt = 0; nt < 4; ++nt)
        acc[mt][nt] = __builtin_amdgcn_mfma_f32_16x16x32_bf16(av[mt], bv[nt], acc[mt][nt], 0, 0, 0);
    int tmp = c0; c0 = c1; c1 = c2; c2 = tmp;
  }

  // epilogue: exp (pad bias = -1e30 -> e=0), predicated scatter store, diagonal zero,
  // per-row partial sums
  int w1 = w & 1;
  float ab[4]; int kc[4];
#pragma unroll
  for (int nt = 0; nt < 4; ++nt) {
    int k = n0 + wc + nt * 16 + lr;
    kc[nt] = k;
    ab[nt] = (k < cPM1) ? att_b[k] : -1e30f;
  }
#pragma unroll
  for (int mt = 0; mt < 4; ++mt) {
#pragma unroll
    for (int r = 0; r < 4; ++r) {
      int i = m0 + wr + mt * 16 + lg * 4 + r;
      int il = i - pp_base;
      bool rowok = (unsigned)(i - m_base) < (unsigned)m_count;
      int pl = i % cP;
      size_t rowbase = (size_t)il * cNPAD;
      float s = 0.f;
#pragma unroll
      for (int nt = 0; nt < 4; ++nt) {
        int k = kc[nt];
        float e = __expf(acc[mt][nt][r] + ab[nt]);
        s += e;
        int j = k + (k >= pl ? 1 : 0);
        if (rowok && j < cNPAD) Pp[rowbase + j] = f2bf(e);
        // diagonal zero: position pl is never hit by the scatter
        if (rowok && (k == pl || (k == cPM1 - 1 && pl == cPM1)))
          Pp[rowbase + pl] = 0;
      }
      s += __shfl_xor(s, 1); s += __shfl_xor(s, 2);
      s += __shfl_xor(s, 4); s += __shfl_xor(s, 8);
      if (lr == 0 && rowok)
        partial[(size_t)(ntile * 2 + w1) * cM + il] = s;
    }
  }
}

// ---------------- GEMM 2 (3-buf pipelined): att_feat = (Pp @ featT^T) / rowsum
// rowsum computed in-block from the 44 partial slots (k_denom folded in)
__global__ __launch_bounds__(256, 4) void k_gemm_pv2(
    const ushort_t* __restrict__ Pp, const ushort_t* __restrict__ featT,
    const float* __restrict__ partial, ushort_t* __restrict__ af,
    int b_base, int pp_base, int ft_base, int af_base) {
  __shared__ __align__(16) ushort_t lds[3][8192];
  __shared__ float sden[128];
  int wg = xcd_swz(blockIdx.x, gridDim.x);
  int ntile = wg % 6;
  int t6 = wg / 6;
  int mtile = t6 % 22;
  int b = b_base + t6 / 22;
  int tid = threadIdx.x;
  int w = tid >> 6, l = tid & 63, lr = l & 15, lg = l >> 4;
  int wr = (w >> 1) * 64, wc = (w & 1) * 64;
  int m0l = mtile * 128;
  int n0 = ntile * 128;
  int bP = b * cP - pp_base;

  // denominator for this block's 128 rows
  if (tid < 128) {
    int p = m0l + tid;
    float s = 1.f;
    if (p < cP) {
      s = 0.f;
#pragma unroll 4
      for (int q = 0; q < 44; ++q) s += partial[(size_t)q * cM + bP + p];
    }
    sden[tid] = s;
  }

  int srow = w * 16 + (l >> 2);
  int scol = ((l & 3) * 8) ^ swz8(srow);
  const ushort_t* a0 = Pp + (size_t)(bP + imin(m0l + srow, cP - 1)) * cNPAD + scol;
  const ushort_t* a1 = Pp + (size_t)(bP + imin(m0l + 64 + srow, cP - 1)) * cNPAD + scol;
  const ushort_t* b0 = featT + ((size_t)(b - ft_base) * cFTR + n0 + srow) * cNPAD + scol;
  const ushort_t* b1 = featT + ((size_t)(b - ft_base) * cFTR + n0 + 64 + srow) * cNPAD + scol;
  int w512 = w * 512;

  int offA[4], offB[4];
#pragma unroll
  for (int mt = 0; mt < 4; ++mt) {
    int row = wr + mt * 16 + lr;
    offA[mt] = row * 32 + ((lg * 8) ^ swz8(row));
  }
#pragma unroll
  for (int nt = 0; nt < 4; ++nt) {
    int row = wc + nt * 16 + lr;
    offB[nt] = 4096 + row * 32 + ((lg * 8) ^ swz8(row));
  }

  floatx4 acc[4][4];
  floatx4 zero = {0.f, 0.f, 0.f, 0.f};
#pragma unroll
  for (int a = 0; a < 4; ++a)
#pragma unroll
    for (int q = 0; q < 4; ++q) acc[a][q] = zero;

  auto stage = [&](int buf) {
    ushort_t* L = &lds[buf][w512];
    gload16(a0, L); gload16(a1, L + 2048);
    gload16(b0, L + 4096); gload16(b1, L + 6144);
    a0 += 32; a1 += 32; b0 += 32; b1 += 32;
  };

  stage(0); stage(1);
  int c0 = 0, c1 = 1, c2 = 2;
  constexpr int NK = cP / 32;  // 87 (pad cols never read)
  for (int t = 0; t < NK; ++t) {
    if (t + 1 < NK) PIPE_BAR4(); else PIPE_BAR0();
    if (t + 2 < NK) stage(c2);
    const ushort_t* Lc = lds[c0];
    short8 av[4], bv[4];
#pragma unroll
    for (int mt = 0; mt < 4; ++mt) av[mt] = *(const short8*)(Lc + offA[mt]);
#pragma unroll
    for (int nt = 0; nt < 4; ++nt) bv[nt] = *(const short8*)(Lc + offB[nt]);
#pragma unroll
    for (int mt = 0; mt < 4; ++mt)
#pragma unroll
      for (int nt = 0; nt < 4; ++nt)
        acc[mt][nt] = __builtin_amdgcn_mfma_f32_16x16x32_bf16(av[mt], bv[nt], acc[mt][nt], 0, 0, 0);
    int tmp = c0; c0 = c1; c1 = c2; c2 = tmp;
  }

#pragma unroll
  for (int mt = 0; mt < 4; ++mt)
#pragma unroll
    for (int r = 0; r < 4; ++r) {
      int lp = wr + mt * 16 + lg * 4 + r;
      int p = m0l + lp;
      if (p >= cP) continue;
      float rdn = __builtin_amdgcn_rcpf(sden[lp]);
#pragma unroll
      for (int nt = 0; nt < 4; ++nt) {
        int dd = n0 + wc + nt * 16 + lr;
        if (dd < cD)
          af[((size_t)(b * cP + p) - af_base) * cD + dd] = f2bf(acc[mt][nt][r] * rdn);
      }
    }
}

// ---------------- GEMM 3 (staged A): [att_feat|feat] @ Wt^T + epilogue
__global__ __launch_bounds__(256, 4) void k_gemm_out(
    const ushort_t* __restrict__ af, const ushort_t* __restrict__ feat,
    const ushort_t* __restrict__ Wt,
    const float* __restrict__ reg_b, const float* __restrict__ cls_b,
    const float* __restrict__ anchors,
    float* __restrict__ out0, float* __restrict__ out1,
    float* __restrict__ out2, float* __restrict__ out3,
    int m_base, int m_count, int af_base) {
  __shared__ __align__(16) ushort_t sA[2][128 * 32];
  int tid = threadIdx.x;
  int w = tid >> 6, l = tid & 63, lr = l & 15, lg = l >> 4;
  int wr = w * 32;
  int m0 = m_base + blockIdx.x * 128;
  int lastRow = m_base + m_count - 1;

  int srow = w * 16 + (l >> 2), scol = (l & 3) * 8;
  const ushort_t* pa0_af = af + (size_t)(imin(m0 + srow, lastRow) - af_base) * cD + scol;
  const ushort_t* pa1_af = af + (size_t)(imin(m0 + 64 + srow, lastRow) - af_base) * cD + scol;
  const ushort_t* pa0_f  = feat + (size_t)imin(m0 + srow, lastRow) * cD + scol;
  const ushort_t* pa1_f  = feat + (size_t)imin(m0 + 64 + srow, lastRow) * cD + scol;
  int lbase = w * 512;

  floatx4 zero = {0.f, 0.f, 0.f, 0.f};
  floatx4 acc[2][5];
#pragma unroll
  for (int a = 0; a < 2; ++a)
#pragma unroll
    for (int q = 0; q < 5; ++q) acc[a][q] = zero;

  auto stageA = [&](int buf, int kk) {
    const ushort_t *s0, *s1;
    if (kk < 22) { s0 = pa0_af + kk * 32; s1 = pa1_af + kk * 32; }
    else         { s0 = pa0_f + (kk - 22) * 32; s1 = pa1_f + (kk - 22) * 32; }
    gload16(s0, &sA[buf][lbase]);
    gload16(s1, &sA[buf][lbase + 2048]);
  };

  stageA(0, 0);
  __syncthreads();
  int cur = 0;
  for (int kk = 0; kk < 44; ++kk) {
    if (kk + 1 < 44) stageA(cur ^ 1, kk + 1);
    int kb = kk * 32 + lg * 8;
    short8 avv[2];
#pragma unroll
    for (int mt = 0; mt < 2; ++mt)
      avv[mt] = *(const short8*)&sA[cur][(wr + mt * 16 + lr) * 32 + lg * 8];
#pragma unroll
    for (int nt = 0; nt < 5; ++nt) {
      short8 bvv = *(const short8*)(Wt + (size_t)(nt * 16 + lr) * 1408 + kb);
#pragma unroll
      for (int mt = 0; mt < 2; ++mt)
        acc[mt][nt] = __builtin_amdgcn_mfma_f32_16x16x32_bf16(avv[mt], bvv, acc[mt][nt], 0, 0, 0);
    }
    __syncthreads();
    cur ^= 1;
  }

#pragma unroll
  for (int mt = 0; mt < 2; ++mt)
#pragma unroll
    for (int nt = 0; nt < 5; ++nt)
#pragma unroll
      for (int r = 0; r < 4; ++r) {
        int i = m0 + wr + mt * 16 + lg * 4 + r;
        if (i - m_base >= m_count) continue;
        int o = nt * 16 + lr;
        int p = i % cP;
        float v = acc[mt][nt][r];
        const float* an = anchors + (size_t)p * 74;
        if (o == 0)        { out2[i] = an[1] + v + reg_b[0]; out1[i] = an[0]; }
        else if (o < 73)   { out0[(size_t)i * 72 + (o - 1)] = an[1 + o] + v + reg_b[o]; }
        else if (o == 73)  { out3[(size_t)i * 2]     = v + cls_b[0]; }
        else if (o == 74)  { out3[(size_t)i * 2 + 1] = v + cls_b[1]; }
      }
}

extern "C" void kernel_launch(void* const* d_in, const int* in_sizes, int n_in,
                              void* d_out, int out_size, void* d_ws, size_t ws_size,
                              hipStream_t stream) {
  const float* x       = (const float*)d_in[0];
  const float* conv_w  = (const float*)d_in[1];
  const float* conv_b  = (const float*)d_in[2];
  const float* att_w   = (const float*)d_in[3];
  const float* att_b   = (const float*)d_in[4];
  const float* cls_w   = (const float*)d_in[5];
  const float* cls_b   = (const float*)d_in[6];
  const float* reg_w   = (const float*)d_in[7];
  const float* reg_b   = (const float*)d_in[8];
  const float* anchors = (const float*)d_in[9];
  const int*   cut_x   = (const int*)d_in[10];
  const unsigned char* invalid = (const unsigned char*)d_in[11];
  float* out0 = (float*)d_out;
  float* out1 = out0 + (size_t)cM * 72;
  float* out2 = out1 + cM;
  float* out3 = out2 + cM;

  size_t off = 0;
  char* base = (char*)d_ws;
  auto carve = [&](size_t bytes) -> void* {
    void* r = base + off; off += (bytes + 255) & ~(size_t)255; return r;
  };
  float* fbuf            = (float*)carve((size_t)cNB * cAFC * cFH * cFW * 4);
  ushort_t* feat         = (ushort_t*)carve((size_t)cM * cD * 2);
  ushort_t* attw         = (ushort_t*)carve((size_t)cNPAD * cD * 2);
  ushort_t* Wt           = (ushort_t*)carve((size_t)80 * 1408 * 2);
  float* partial         = (float*)carve((size_t)44 * cM * 4);

  size_t featT_full = (size_t)cNB * cFTR * cNPAD * 2, featT_one = (size_t)cFTR * cNPAD * 2;
  size_t af_full    = (size_t)cM * cD * 2,            af_one    = (size_t)cP * cD * 2;
  size_t pp_full    = (size_t)cM * cNPAD * 2,         pp_one    = (size_t)cNPAD * cNPAD * 2;

  size_t needA = off + featT_full + af_full + pp_full;
  size_t needB = off + featT_full + af_full + pp_one;
  int mode = (ws_size >= needA) ? 0 : ((ws_size >= needB) ? 1 : 2);

  ushort_t *featT, *af, *Pp;
  if (mode == 0)      { featT = (ushort_t*)carve(featT_full); af = (ushort_t*)carve(af_full); Pp = (ushort_t*)carve(pp_full); }
  else if (mode == 1) { featT = (ushort_t*)carve(featT_full); af = (ushort_t*)carve(af_full); Pp = (ushort_t*)carve(pp_one); }
  else                { featT = (ushort_t*)carve(featT_one);  af = (ushort_t*)carve(af_one);  Pp = (ushort_t*)carve(pp_one); }

  k_conv4<<<(cNB * 16 * 220 + 255) / 256, 256, 0, stream>>>(x, conv_w, conv_b, fbuf);
  k_prep_w<<<(cNPAD * cD + 80 * 1408 + 255) / 256, 256, 0, stream>>>(att_w, reg_w, cls_w, attw, Wt);

  if (mode == 0) {
    k_gatherT<<<dim3(44, 11, 8), 256, 0, stream>>>(fbuf, cut_x, invalid, feat, featT, 0);
    k_gemm_s2<<<174 * 22, 256, 0, stream>>>(feat, attw, att_b, Pp, partial, 0, cM, 0);
    k_gemm_pv2<<<8 * 22 * 6, 256, 0, stream>>>(Pp, featT, partial, af, 0, 0, 0, 0);
    k_gemm_out<<<174, 256, 0, stream>>>(af, feat, Wt, reg_b, cls_b, anchors,
                                        out0, out1, out2, out3, 0, cM, 0);
  } else if (mode == 1) {
    k_gatherT<<<dim3(44, 11, 8), 256, 0, stream>>>(fbuf, cut_x, invalid, feat, featT, 0);
    for (int b = 0; b < cNB; ++b) {
      k_gemm_s2<<<22 * 22, 256, 0, stream>>>(feat, attw, att_b, Pp, partial, b * cP, cP, b * cP);
      k_gemm_pv2<<<22 * 6, 256, 0, stream>>>(Pp, featT, partial, af, b, b * cP, 0, 0);
    }
    k_gemm_out<<<174, 256, 0, stream>>>(af, feat, Wt, reg_b, cls_b, anchors,
                                        out0, out1, out2, out3, 0, cM, 0);
  } else {
    for (int b = 0; b < cNB; ++b) {
      k_gatherT<<<dim3(44, 11, 1), 256, 0, stream>>>(fbuf, cut_x, invalid, feat, featT, b);
      k_gemm_s2<<<22 * 22, 256, 0, stream>>>(feat, attw, att_b, Pp, partial, b * cP, cP, b * cP);
      k_gemm_pv2<<<22 * 6, 256, 0, stream>>>(Pp, featT, partial, af, b, b * cP, b, b * cP);
      k_gemm_out<<<22, 256, 0, stream>>>(af, feat, Wt, reg_b, cls_b, anchors,
                                         out0, out1, out2, out3, b * cP, cP, b * cP);
    }
  }
}

// Round 11
// 446.430 us; speedup vs baseline: 1.1384x; 1.0679x over previous
//
#include <hip/hip_runtime.h>
#include <stdint.h>

typedef short short8 __attribute__((ext_vector_type(8)));
typedef float floatx4 __attribute__((ext_vector_type(4)));
typedef unsigned short ushort_t;

constexpr int cFH = 11, cFW = 20, cP = 2784, cPM1 = 2783, cD = 704;
constexpr int cAFC = 64, cBBC = 512, cNB = 8, cNPAD = 2816, cM = 22272;
constexpr int cFTR = 768;   // featT padded rows

static __device__ __forceinline__ unsigned short f2bf(float f) {
  union { float f; unsigned u; } v; v.f = f;
  unsigned r = v.u + 0x7fffu + ((v.u >> 16) & 1u);
  return (unsigned short)(r >> 16);
}
static __device__ __forceinline__ int imin(int a, int b) { return a < b ? a : b; }
// LDS XOR swizzle: position (row, pcol) holds global col pcol ^ swz8(row)
static __device__ __forceinline__ int swz8(int row) { return ((row >> 1) & 3) << 3; }

// bijective XCD-chunk swizzle (m204)
static __device__ __forceinline__ int xcd_swz(int orig, int total) {
  int q = total >> 3, r = total & 7;
  int xcd = orig & 7, pos = orig >> 3;
  return (xcd < r ? xcd * (q + 1) : r * (q + 1) + (xcd - r) * q) + pos;
}

// async global->LDS, 16B per lane, wave-uniform LDS base + lane*16
static __device__ __forceinline__ void gload16(const ushort_t* g, ushort_t* l) {
  __builtin_amdgcn_global_load_lds(
      (const __attribute__((address_space(1))) unsigned int*)g,
      (__attribute__((address_space(3))) unsigned int*)l, 16, 0, 0);
}

#define PIPE_BAR4() asm volatile("s_waitcnt vmcnt(4)\n\ts_barrier" ::: "memory")
#define PIPE_BAR2() asm volatile("s_waitcnt vmcnt(2)\n\ts_barrier" ::: "memory")
#define PIPE_BAR0() asm volatile("s_waitcnt vmcnt(0)\n\ts_barrier" ::: "memory")

// ---------------- 1x1 conv, 4 output channels per thread
__global__ void k_conv4(const float* __restrict__ x, const float* __restrict__ w,
                        const float* __restrict__ bias, float* __restrict__ f) {
  int idx = blockIdx.x * 256 + threadIdx.x;
  if (idx >= cNB * 16 * 220) return;
  int yx = idx % 220;
  int og = (idx / 220) % 16;
  int b  = idx / (220 * 16);
  int o0 = og * 4;
  const float* xp = x + (size_t)b * cBBC * 220 + yx;
  const float* w0 = w + (size_t)o0 * cBBC;
  const float* w1 = w0 + cBBC;
  const float* w2 = w1 + cBBC;
  const float* w3 = w2 + cBBC;
  float a0 = 0.f, a1 = 0.f, a2 = 0.f, a3 = 0.f;
#pragma unroll 4
  for (int c = 0; c < cBBC; ++c) {
    float xv = xp[(size_t)c * 220];
    a0 += xv * w0[c]; a1 += xv * w1[c]; a2 += xv * w2[c]; a3 += xv * w3[c];
  }
  f[((size_t)(b * cAFC + o0) * 220) + yx]     = a0 + bias[o0];
  f[((size_t)(b * cAFC + o0 + 1) * 220) + yx] = a1 + bias[o0 + 1];
  f[((size_t)(b * cAFC + o0 + 2) * 220) + yx] = a2 + bias[o0 + 2];
  f[((size_t)(b * cAFC + o0 + 3) * 220) + yx] = a3 + bias[o0 + 3];
}

// ---------------- fused gather + transpose: writes feat [22272][704] AND featT [bz][768][2816]
__global__ void k_gatherT(const float* __restrict__ f, const int* __restrict__ cut_x,
                          const unsigned char* __restrict__ invalid,
                          ushort_t* __restrict__ feat, ushort_t* __restrict__ featT,
                          int b_base) {
  __shared__ ushort_t tile[64][66];
  int bz = blockIdx.z;
  int b  = b_base + bz;
  int p0 = blockIdx.x * 64, d0 = blockIdx.y * 64;
  int t = threadIdx.x;
#pragma unroll
  for (int m = 0; m < 16; ++m) {
    int idx = t + m * 256; int r = idx >> 6, c = idx & 63;
    int p = p0 + r, d = d0 + c;
    ushort_t v = 0;
    if (p < cP) {
      int o = d / cFH, i2 = d - o * cFH;
      int cx = cut_x[p * cFH + i2];
      float vv = invalid[p * cFH + i2] ? 0.f
               : f[((size_t)(b * cAFC + o) * cFH + i2) * cFW + cx];
      v = f2bf(vv);
      feat[((size_t)b * cP + p) * cD + d] = v;
    }
    tile[r][c] = v;
  }
  __syncthreads();
#pragma unroll
  for (int m = 0; m < 16; ++m) {
    int idx = t + m * 256; int r = idx >> 6, c = idx & 63;
    featT[((size_t)bz * cFTR + d0 + r) * cNPAD + p0 + c] = tile[c][r];
  }
}

// ---------------- att_w -> bf16 padded [2816][704]  +  Wt [80][1408]
__global__ void k_prep_w(const float* __restrict__ att_w, const float* __restrict__ reg_w,
                         const float* __restrict__ cls_w,
                         ushort_t* __restrict__ attw, ushort_t* __restrict__ Wt) {
  int idx = blockIdx.x * 256 + threadIdx.x;
  constexpr int n1 = cNPAD * cD;
  if (idx < n1) {
    int r = idx / cD;
    attw[idx] = (r < cPM1) ? f2bf(att_w[idx]) : (ushort_t)0;
  } else {
    int j = idx - n1;
    if (j < 80 * 1408) {
      int r = j / 1408, k = j % 1408;
      float v = 0.f;
      if (r < 73) v = reg_w[(size_t)r * 1408 + k];
      else if (r < 75) v = cls_w[(size_t)(r - 73) * 1408 + k];
      Wt[j] = f2bf(v);
    }
  }
}

// ---------------- denom[i] = sum of 44 partial slots
__global__ void k_denom(const float* __restrict__ partial, float* __restrict__ denom, int n) {
  int i = blockIdx.x * 256 + threadIdx.x;
  if (i >= n) return;
  float s = 0.f;
#pragma unroll 4
  for (int q = 0; q < 44; ++q) s += partial[(size_t)q * cM + i];
  denom[i] = s;
}

// ---------------- GEMM 1 (3-buf pipelined): S = feat @ attw^T; exp; scatter+diag; partials
__global__ __launch_bounds__(256, 4) void k_gemm_s2(
    const ushort_t* __restrict__ feat, const ushort_t* __restrict__ attw,
    const float* __restrict__ att_b, ushort_t* __restrict__ Pp,
    float* __restrict__ partial, int m_base, int m_count, int pp_base) {
  __shared__ __align__(16) ushort_t lds[3][8192];
  int wg = xcd_swz(blockIdx.x, gridDim.x);
  int ntile = wg % 22, mtile = wg / 22;
  int tid = threadIdx.x;
  int w = tid >> 6, l = tid & 63, lr = l & 15, lg = l >> 4;
  int wr = (w >> 1) * 64, wc = (w & 1) * 64;
  int m0 = m_base + mtile * 128;
  int n0 = ntile * 128;
  int rmaxA = m_base + m_count - 1;

  int srow = w * 16 + (l >> 2);
  int scol = ((l & 3) * 8) ^ swz8(srow);   // pre-swizzled global source col
  const ushort_t* a0 = feat + (size_t)imin(m0 + srow, rmaxA) * cD + scol;
  const ushort_t* a1 = feat + (size_t)imin(m0 + 64 + srow, rmaxA) * cD + scol;
  const ushort_t* b0 = attw + (size_t)(n0 + srow) * cD + scol;
  const ushort_t* b1 = attw + (size_t)(n0 + 64 + srow) * cD + scol;
  int w512 = w * 512;

  int offA[4], offB[4];
#pragma unroll
  for (int mt = 0; mt < 4; ++mt) {
    int row = wr + mt * 16 + lr;
    offA[mt] = row * 32 + ((lg * 8) ^ swz8(row));
  }
#pragma unroll
  for (int nt = 0; nt < 4; ++nt) {
    int row = wc + nt * 16 + lr;
    offB[nt] = 4096 + row * 32 + ((lg * 8) ^ swz8(row));
  }

  floatx4 acc[4][4];
  floatx4 zero = {0.f, 0.f, 0.f, 0.f};
#pragma unroll
  for (int a = 0; a < 4; ++a)
#pragma unroll
    for (int q = 0; q < 4; ++q) acc[a][q] = zero;

  auto stage = [&](int buf) {
    ushort_t* L = &lds[buf][w512];
    gload16(a0, L); gload16(a1, L + 2048);
    gload16(b0, L + 4096); gload16(b1, L + 6144);
    a0 += 32; a1 += 32; b0 += 32; b1 += 32;
  };

  stage(0); stage(1);
  int c0 = 0, c1 = 1, c2 = 2;
  constexpr int NK = cD / 32;  // 22
  for (int t = 0; t < NK; ++t) {
    if (t + 1 < NK) PIPE_BAR4(); else PIPE_BAR0();
    if (t + 2 < NK) stage(c2);
    const ushort_t* Lc = lds[c0];
    short8 av[4], bv[4];
#pragma unroll
    for (int mt = 0; mt < 4; ++mt) av[mt] = *(const short8*)(Lc + offA[mt]);
#pragma unroll
    for (int nt = 0; nt < 4; ++nt) bv[nt] = *(const short8*)(Lc + offB[nt]);
#pragma unroll
    for (int mt = 0; mt < 4; ++mt)
#pragma unroll
      for (int nt = 0; nt < 4; ++nt)
        acc[mt][nt] = __builtin_amdgcn_mfma_f32_16x16x32_bf16(av[mt], bv[nt], acc[mt][nt], 0, 0, 0);
    int tmp = c0; c0 = c1; c1 = c2; c2 = tmp;
  }

  // epilogue: exp (pad bias = -1e30 -> e=0), predicated scatter store, diagonal zero,
  // per-row partial sums
  int w1 = w & 1;
  float ab[4]; int kc[4];
#pragma unroll
  for (int nt = 0; nt < 4; ++nt) {
    int k = n0 + wc + nt * 16 + lr;
    kc[nt] = k;
    ab[nt] = (k < cPM1) ? att_b[k] : -1e30f;
  }
#pragma unroll
  for (int mt = 0; mt < 4; ++mt) {
#pragma unroll
    for (int r = 0; r < 4; ++r) {
      int i = m0 + wr + mt * 16 + lg * 4 + r;
      int il = i - pp_base;
      bool rowok = (unsigned)(i - m_base) < (unsigned)m_count;
      int pl = i % cP;
      size_t rowbase = (size_t)il * cNPAD;
      float s = 0.f;
#pragma unroll
      for (int nt = 0; nt < 4; ++nt) {
        int k = kc[nt];
        float e = __expf(acc[mt][nt][r] + ab[nt]);
        s += e;
        int j = k + (k >= pl ? 1 : 0);
        if (rowok && j < cNPAD) Pp[rowbase + j] = f2bf(e);
        // diagonal slot is never hit by the scatter -> zero it exactly once
        if (rowok && (k == pl || (k == cPM1 - 1 && pl == cPM1)))
          Pp[rowbase + pl] = 0;
      }
      s += __shfl_xor(s, 1); s += __shfl_xor(s, 2);
      s += __shfl_xor(s, 4); s += __shfl_xor(s, 8);
      if (lr == 0 && rowok)
        partial[(size_t)(ntile * 2 + w1) * cM + il] = s;
    }
  }
}

// ---------------- GEMM 2 (3-buf pipelined): att_feat = (Pp @ featT^T) / denom
__global__ __launch_bounds__(256, 4) void k_gemm_pv2(
    const ushort_t* __restrict__ Pp, const ushort_t* __restrict__ featT,
    const float* __restrict__ denom, ushort_t* __restrict__ af,
    int b_base, int pp_base, int ft_base, int af_base) {
  __shared__ __align__(16) ushort_t lds[3][8192];
  int wg = xcd_swz(blockIdx.x, gridDim.x);
  int ntile = wg % 6;
  int t6 = wg / 6;
  int mtile = t6 % 22;
  int b = b_base + t6 / 22;
  int tid = threadIdx.x;
  int w = tid >> 6, l = tid & 63, lr = l & 15, lg = l >> 4;
  int wr = (w >> 1) * 64, wc = (w & 1) * 64;
  int m0l = mtile * 128;
  int n0 = ntile * 128;
  int bP = b * cP - pp_base;

  int srow = w * 16 + (l >> 2);
  int scol = ((l & 3) * 8) ^ swz8(srow);
  const ushort_t* a0 = Pp + (size_t)(bP + imin(m0l + srow, cP - 1)) * cNPAD + scol;
  const ushort_t* a1 = Pp + (size_t)(bP + imin(m0l + 64 + srow, cP - 1)) * cNPAD + scol;
  const ushort_t* b0 = featT + ((size_t)(b - ft_base) * cFTR + n0 + srow) * cNPAD + scol;
  const ushort_t* b1 = featT + ((size_t)(b - ft_base) * cFTR + n0 + 64 + srow) * cNPAD + scol;
  int w512 = w * 512;

  int offA[4], offB[4];
#pragma unroll
  for (int mt = 0; mt < 4; ++mt) {
    int row = wr + mt * 16 + lr;
    offA[mt] = row * 32 + ((lg * 8) ^ swz8(row));
  }
#pragma unroll
  for (int nt = 0; nt < 4; ++nt) {
    int row = wc + nt * 16 + lr;
    offB[nt] = 4096 + row * 32 + ((lg * 8) ^ swz8(row));
  }

  floatx4 acc[4][4];
  floatx4 zero = {0.f, 0.f, 0.f, 0.f};
#pragma unroll
  for (int a = 0; a < 4; ++a)
#pragma unroll
    for (int q = 0; q < 4; ++q) acc[a][q] = zero;

  auto stage = [&](int buf) {
    ushort_t* L = &lds[buf][w512];
    gload16(a0, L); gload16(a1, L + 2048);
    gload16(b0, L + 4096); gload16(b1, L + 6144);
    a0 += 32; a1 += 32; b0 += 32; b1 += 32;
  };

  stage(0); stage(1);
  int c0 = 0, c1 = 1, c2 = 2;
  constexpr int NK = cP / 32;  // 87 (pad cols never read)
  for (int t = 0; t < NK; ++t) {
    if (t + 1 < NK) PIPE_BAR4(); else PIPE_BAR0();
    if (t + 2 < NK) stage(c2);
    const ushort_t* Lc = lds[c0];
    short8 av[4], bv[4];
#pragma unroll
    for (int mt = 0; mt < 4; ++mt) av[mt] = *(const short8*)(Lc + offA[mt]);
#pragma unroll
    for (int nt = 0; nt < 4; ++nt) bv[nt] = *(const short8*)(Lc + offB[nt]);
#pragma unroll
    for (int mt = 0; mt < 4; ++mt)
#pragma unroll
      for (int nt = 0; nt < 4; ++nt)
        acc[mt][nt] = __builtin_amdgcn_mfma_f32_16x16x32_bf16(av[mt], bv[nt], acc[mt][nt], 0, 0, 0);
    int tmp = c0; c0 = c1; c1 = c2; c2 = tmp;
  }

#pragma unroll
  for (int mt = 0; mt < 4; ++mt)
#pragma unroll
    for (int r = 0; r < 4; ++r) {
      int p = m0l + wr + mt * 16 + lg * 4 + r;
      if (p >= cP) continue;
      float rdn = denom[bP + p];
#pragma unroll
      for (int nt = 0; nt < 4; ++nt) {
        int dd = n0 + wc + nt * 16 + lr;
        if (dd < cD)
          af[((size_t)(b * cP + p) - af_base) * cD + dd] = f2bf(acc[mt][nt][r] / rdn);
      }
    }
}

// ---------------- GEMM 3 (3-buf pipelined A): [att_feat|feat] @ Wt^T + epilogue
__global__ __launch_bounds__(256, 4) void k_gemm_out(
    const ushort_t* __restrict__ af, const ushort_t* __restrict__ feat,
    const ushort_t* __restrict__ Wt,
    const float* __restrict__ reg_b, const float* __restrict__ cls_b,
    const float* __restrict__ anchors,
    float* __restrict__ out0, float* __restrict__ out1,
    float* __restrict__ out2, float* __restrict__ out3,
    int m_base, int m_count, int af_base) {
  __shared__ __align__(16) ushort_t sA[3][4096];
  int tid = threadIdx.x;
  int w = tid >> 6, l = tid & 63, lr = l & 15, lg = l >> 4;
  int wr = w * 32;
  int m0 = m_base + blockIdx.x * 128;
  int lastRow = m_base + m_count - 1;

  int srow = w * 16 + (l >> 2);
  int scol = ((l & 3) * 8) ^ swz8(srow);
  const ushort_t* pa0_af = af + (size_t)(imin(m0 + srow, lastRow) - af_base) * cD + scol;
  const ushort_t* pa1_af = af + (size_t)(imin(m0 + 64 + srow, lastRow) - af_base) * cD + scol;
  const ushort_t* pa0_f  = feat + (size_t)imin(m0 + srow, lastRow) * cD + scol;
  const ushort_t* pa1_f  = feat + (size_t)imin(m0 + 64 + srow, lastRow) * cD + scol;
  int lbase = w * 512;

  int offO[2];
#pragma unroll
  for (int mt = 0; mt < 2; ++mt) {
    int row = wr + mt * 16 + lr;
    offO[mt] = row * 32 + ((lg * 8) ^ swz8(row));
  }

  floatx4 zero = {0.f, 0.f, 0.f, 0.f};
  floatx4 acc[2][5];
#pragma unroll
  for (int a = 0; a < 2; ++a)
#pragma unroll
    for (int q = 0; q < 5; ++q) acc[a][q] = zero;

  auto stageA = [&](int buf, int kk) {
    const ushort_t *s0, *s1;
    if (kk < 22) { s0 = pa0_af + kk * 32; s1 = pa1_af + kk * 32; }
    else         { s0 = pa0_f + (kk - 22) * 32; s1 = pa1_f + (kk - 22) * 32; }
    gload16(s0, &sA[buf][lbase]);
    gload16(s1, &sA[buf][lbase + 2048]);
  };

  stageA(0, 0); stageA(1, 1);
  int c0 = 0, c1 = 1, c2 = 2;
  for (int kk = 0; kk < 44; ++kk) {
    if (kk + 1 < 44) PIPE_BAR2(); else PIPE_BAR0();
    int kb = kk * 32 + lg * 8;
    // issue Wt fragment loads FIRST so their completion wait is a counted vmcnt
    // that does not drain the staging queue
    short8 bvv[5];
#pragma unroll
    for (int nt = 0; nt < 5; ++nt)
      bvv[nt] = *(const short8*)(Wt + (size_t)(nt * 16 + lr) * 1408 + kb);
    if (kk + 2 < 44) stageA(c2, kk + 2);
    short8 avv[2];
#pragma unroll
    for (int mt = 0; mt < 2; ++mt)
      avv[mt] = *(const short8*)&sA[c0][offO[mt]];
#pragma unroll
    for (int nt = 0; nt < 5; ++nt)
#pragma unroll
      for (int mt = 0; mt < 2; ++mt)
        acc[mt][nt] = __builtin_amdgcn_mfma_f32_16x16x32_bf16(avv[mt], bvv[nt], acc[mt][nt], 0, 0, 0);
    int tmp = c0; c0 = c1; c1 = c2; c2 = tmp;
  }

#pragma unroll
  for (int mt = 0; mt < 2; ++mt)
#pragma unroll
    for (int nt = 0; nt < 5; ++nt)
#pragma unroll
      for (int r = 0; r < 4; ++r) {
        int i = m0 + wr + mt * 16 + lg * 4 + r;
        if (i - m_base >= m_count) continue;
        int o = nt * 16 + lr;
        int p = i % cP;
        float v = acc[mt][nt][r];
        const float* an = anchors + (size_t)p * 74;
        if (o == 0)        { out2[i] = an[1] + v + reg_b[0]; out1[i] = an[0]; }
        else if (o < 73)   { out0[(size_t)i * 72 + (o - 1)] = an[1 + o] + v + reg_b[o]; }
        else if (o == 73)  { out3[(size_t)i * 2]     = v + cls_b[0]; }
        else if (o == 74)  { out3[(size_t)i * 2 + 1] = v + cls_b[1]; }
      }
}

extern "C" void kernel_launch(void* const* d_in, const int* in_sizes, int n_in,
                              void* d_out, int out_size, void* d_ws, size_t ws_size,
                              hipStream_t stream) {
  const float* x       = (const float*)d_in[0];
  const float* conv_w  = (const float*)d_in[1];
  const float* conv_b  = (const float*)d_in[2];
  const float* att_w   = (const float*)d_in[3];
  const float* att_b   = (const float*)d_in[4];
  const float* cls_w   = (const float*)d_in[5];
  const float* cls_b   = (const float*)d_in[6];
  const float* reg_w   = (const float*)d_in[7];
  const float* reg_b   = (const float*)d_in[8];
  const float* anchors = (const float*)d_in[9];
  const int*   cut_x   = (const int*)d_in[10];
  const unsigned char* invalid = (const unsigned char*)d_in[11];
  float* out0 = (float*)d_out;
  float* out1 = out0 + (size_t)cM * 72;
  float* out2 = out1 + cM;
  float* out3 = out2 + cM;

  size_t off = 0;
  char* base = (char*)d_ws;
  auto carve = [&](size_t bytes) -> void* {
    void* r = base + off; off += (bytes + 255) & ~(size_t)255; return r;
  };
  float* fbuf            = (float*)carve((size_t)cNB * cAFC * cFH * cFW * 4);
  ushort_t* feat         = (ushort_t*)carve((size_t)cM * cD * 2);
  ushort_t* attw         = (ushort_t*)carve((size_t)cNPAD * cD * 2);
  ushort_t* Wt           = (ushort_t*)carve((size_t)80 * 1408 * 2);
  float* partial         = (float*)carve((size_t)44 * cM * 4);
  float* denom           = (float*)carve((size_t)cM * 4);

  size_t featT_full = (size_t)cNB * cFTR * cNPAD * 2, featT_one = (size_t)cFTR * cNPAD * 2;
  size_t af_full    = (size_t)cM * cD * 2,            af_one    = (size_t)cP * cD * 2;
  size_t pp_full    = (size_t)cM * cNPAD * 2,         pp_one    = (size_t)cNPAD * cNPAD * 2;

  size_t needA = off + featT_full + af_full + pp_full;
  size_t needB = off + featT_full + af_full + pp_one;
  int mode = (ws_size >= needA) ? 0 : ((ws_size >= needB) ? 1 : 2);

  ushort_t *featT, *af, *Pp;
  if (mode == 0)      { featT = (ushort_t*)carve(featT_full); af = (ushort_t*)carve(af_full); Pp = (ushort_t*)carve(pp_full); }
  else if (mode == 1) { featT = (ushort_t*)carve(featT_full); af = (ushort_t*)carve(af_full); Pp = (ushort_t*)carve(pp_one); }
  else                { featT = (ushort_t*)carve(featT_one);  af = (ushort_t*)carve(af_one);  Pp = (ushort_t*)carve(pp_one); }

  k_conv4<<<(cNB * 16 * 220 + 255) / 256, 256, 0, stream>>>(x, conv_w, conv_b, fbuf);
  k_prep_w<<<(cNPAD * cD + 80 * 1408 + 255) / 256, 256, 0, stream>>>(att_w, reg_w, cls_w, attw, Wt);

  if (mode == 0) {
    k_gatherT<<<dim3(44, 11, 8), 256, 0, stream>>>(fbuf, cut_x, invalid, feat, featT, 0);
    k_gemm_s2<<<174 * 22, 256, 0, stream>>>(feat, attw, att_b, Pp, partial, 0, cM, 0);
    k_denom<<<(cM + 255) / 256, 256, 0, stream>>>(partial, denom, cM);
    k_gemm_pv2<<<8 * 22 * 6, 256, 0, stream>>>(Pp, featT, denom, af, 0, 0, 0, 0);
    k_gemm_out<<<174, 256, 0, stream>>>(af, feat, Wt, reg_b, cls_b, anchors,
                                        out0, out1, out2, out3, 0, cM, 0);
  } else if (mode == 1) {
    k_gatherT<<<dim3(44, 11, 8), 256, 0, stream>>>(fbuf, cut_x, invalid, feat, featT, 0);
    for (int b = 0; b < cNB; ++b) {
      k_gemm_s2<<<22 * 22, 256, 0, stream>>>(feat, attw, att_b, Pp, partial, b * cP, cP, b * cP);
      k_denom<<<(cP + 255) / 256, 256, 0, stream>>>(partial, denom, cP);
      k_gemm_pv2<<<22 * 6, 256, 0, stream>>>(Pp, featT, denom, af, b, b * cP, 0, 0);
    }
    k_gemm_out<<<174, 256, 0, stream>>>(af, feat, Wt, reg_b, cls_b, anchors,
                                        out0, out1, out2, out3, 0, cM, 0);
  } else {
    for (int b = 0; b < cNB; ++b) {
      k_gatherT<<<dim3(44, 11, 1), 256, 0, stream>>>(fbuf, cut_x, invalid, feat, featT, b);
      k_gemm_s2<<<22 * 22, 256, 0, stream>>>(feat, attw, att_b, Pp, partial, b * cP, cP, b * cP);
      k_denom<<<(cP + 255) / 256, 256, 0, stream>>>(partial, denom, cP);
      k_gemm_pv2<<<22 * 6, 256, 0, stream>>>(Pp, featT, denom, af, b, b * cP, b, b * cP);
      k_gemm_out<<<22, 256, 0, stream>>>(af, feat, Wt, reg_b, cls_b, anchors,
                                         out0, out1, out2, out3, b * cP, cP, b * cP);
    }
  }
}

// Round 12
// 384.428 us; speedup vs baseline: 1.3220x; 1.1613x over previous
//
#include <hip/hip_runtime.h>
#include <stdint.h>

typedef short short8 __attribute__((ext_vector_type(8)));
typedef float floatx4 __attribute__((ext_vector_type(4)));
typedef unsigned short ushort_t;
typedef unsigned char u8;

constexpr int cFH = 11, cFW = 20, cP = 2784, cPM1 = 2783, cD = 704;
constexpr int cAFC = 64, cBBC = 512, cNB = 8, cNPAD = 2816, cM = 22272;
constexpr int cFTR = 768;   // featT padded rows

static __device__ __forceinline__ float bf2f(unsigned short u) {
  union { unsigned u32; float f; } v; v.u32 = ((unsigned)u) << 16; return v.f;
}
static __device__ __forceinline__ unsigned short f2bf(float f) {
  union { float f; unsigned u; } v; v.f = f;
  unsigned r = v.u + 0x7fffu + ((v.u >> 16) & 1u);
  return (unsigned short)(r >> 16);
}
// float -> OCP e4m3 (RNE + saturation in HW)
static __device__ __forceinline__ u8 f2fp8(float f) {
  int v = __builtin_amdgcn_cvt_pk_fp8_f32(f, 0.f, 0, false);
  return (u8)(v & 0xff);
}
static __device__ __forceinline__ int imin(int a, int b) { return a < b ? a : b; }
// bf16 LDS XOR swizzle (kept for gemm_out)
static __device__ __forceinline__ int swz8(int row) { return ((row >> 1) & 3) << 3; }

// bijective XCD-chunk swizzle (m204)
static __device__ __forceinline__ int xcd_swz(int orig, int total) {
  int q = total >> 3, r = total & 7;
  int xcd = orig & 7, pos = orig >> 3;
  return (xcd < r ? xcd * (q + 1) : r * (q + 1) + (xcd - r) * q) + pos;
}

// async global->LDS, 16B per lane, wave-uniform LDS base + lane*16
static __device__ __forceinline__ void gload16(const void* g, void* l) {
  __builtin_amdgcn_global_load_lds(
      (const __attribute__((address_space(1))) unsigned int*)g,
      (__attribute__((address_space(3))) unsigned int*)l, 16, 0, 0);
}

static __device__ __forceinline__ floatx4 mfma_fp8(long a, long b, floatx4 c) {
  return __builtin_amdgcn_mfma_f32_16x16x32_fp8_fp8(a, b, c, 0, 0, 0);
}

#define PIPE_BAR4() asm volatile("s_waitcnt vmcnt(4)\n\ts_barrier" ::: "memory")
#define PIPE_BAR2() asm volatile("s_waitcnt vmcnt(2)\n\ts_barrier" ::: "memory")
#define PIPE_BAR0() asm volatile("s_waitcnt vmcnt(0)\n\ts_barrier" ::: "memory")

constexpr float kFeatScale = 16.f;   // feat8 = feat * 16
constexpr float kAttwScale = 64.f;   // attw8 = att_w * 64
constexpr float kSInv = 1.f / (kFeatScale * kAttwScale);

// ---------------- 1x1 conv, 4 output channels per thread
__global__ void k_conv4(const float* __restrict__ x, const float* __restrict__ w,
                        const float* __restrict__ bias, float* __restrict__ f) {
  int idx = blockIdx.x * 256 + threadIdx.x;
  if (idx >= cNB * 16 * 220) return;
  int yx = idx % 220;
  int og = (idx / 220) % 16;
  int b  = idx / (220 * 16);
  int o0 = og * 4;
  const float* xp = x + (size_t)b * cBBC * 220 + yx;
  const float* w0 = w + (size_t)o0 * cBBC;
  const float* w1 = w0 + cBBC;
  const float* w2 = w1 + cBBC;
  const float* w3 = w2 + cBBC;
  float a0 = 0.f, a1 = 0.f, a2 = 0.f, a3 = 0.f;
#pragma unroll 4
  for (int c = 0; c < cBBC; ++c) {
    float xv = xp[(size_t)c * 220];
    a0 += xv * w0[c]; a1 += xv * w1[c]; a2 += xv * w2[c]; a3 += xv * w3[c];
  }
  f[((size_t)(b * cAFC + o0) * 220) + yx]     = a0 + bias[o0];
  f[((size_t)(b * cAFC + o0 + 1) * 220) + yx] = a1 + bias[o0 + 1];
  f[((size_t)(b * cAFC + o0 + 2) * 220) + yx] = a2 + bias[o0 + 2];
  f[((size_t)(b * cAFC + o0 + 3) * 220) + yx] = a3 + bias[o0 + 3];
}

// ---------------- fused gather + transpose: feat bf16, feat8 fp8, featT8 fp8
__global__ void k_gatherT(const float* __restrict__ f, const int* __restrict__ cut_x,
                          const unsigned char* __restrict__ invalid,
                          ushort_t* __restrict__ feat, u8* __restrict__ feat8,
                          u8* __restrict__ featT8, int b_base) {
  __shared__ ushort_t tile[64][66];
  int bz = blockIdx.z;
  int b  = b_base + bz;
  int p0 = blockIdx.x * 64, d0 = blockIdx.y * 64;
  int t = threadIdx.x;
#pragma unroll
  for (int m = 0; m < 16; ++m) {
    int idx = t + m * 256; int r = idx >> 6, c = idx & 63;
    int p = p0 + r, d = d0 + c;
    ushort_t v = 0;
    if (p < cP) {
      int o = d / cFH, i2 = d - o * cFH;
      int cx = cut_x[p * cFH + i2];
      float vv = invalid[p * cFH + i2] ? 0.f
               : f[((size_t)(b * cAFC + o) * cFH + i2) * cFW + cx];
      v = f2bf(vv);
      feat[((size_t)b * cP + p) * cD + d] = v;
      feat8[((size_t)b * cP + p) * cD + d] = f2fp8(vv * kFeatScale);
    }
    tile[r][c] = v;
  }
  __syncthreads();
#pragma unroll
  for (int m = 0; m < 16; ++m) {
    int idx = t + m * 256; int r = idx >> 6, c = idx & 63;
    float tv = bf2f(tile[c][r]);
    featT8[((size_t)bz * cFTR + d0 + r) * cNPAD + p0 + c] = f2fp8(tv * kFeatScale);
  }
}

// ---------------- att_w -> fp8 (x64) padded [2816][704]  +  Wt bf16 [80][1408]
__global__ void k_prep_w(const float* __restrict__ att_w, const float* __restrict__ reg_w,
                         const float* __restrict__ cls_w,
                         u8* __restrict__ attw8, ushort_t* __restrict__ Wt) {
  int idx = blockIdx.x * 256 + threadIdx.x;
  constexpr int n1 = cNPAD * cD;
  if (idx < n1) {
    int r = idx / cD;
    attw8[idx] = (r < cPM1) ? f2fp8(att_w[idx] * kAttwScale) : (u8)0;
  } else {
    int j = idx - n1;
    if (j < 80 * 1408) {
      int r = j / 1408, k = j % 1408;
      float v = 0.f;
      if (r < 73) v = reg_w[(size_t)r * 1408 + k];
      else if (r < 75) v = cls_w[(size_t)(r - 73) * 1408 + k];
      Wt[j] = f2bf(v);
    }
  }
}

// ---------------- denom[i] = sum of 44 partial slots
__global__ void k_denom(const float* __restrict__ partial, float* __restrict__ denom, int n) {
  int i = blockIdx.x * 256 + threadIdx.x;
  if (i >= n) return;
  float s = 0.f;
#pragma unroll 4
  for (int q = 0; q < 44; ++q) s += partial[(size_t)q * cM + i];
  denom[i] = s;
}

// ---------------- GEMM 1 (fp8, 3-buf): S = feat8 @ attw8^T; exp; scatter+diag; partials
__global__ __launch_bounds__(256, 4) void k_gemm_s2(
    const u8* __restrict__ feat8, const u8* __restrict__ attw8,
    const float* __restrict__ att_b, u8* __restrict__ Pp8,
    float* __restrict__ partial, int m_base, int m_count, int pp_base) {
  __shared__ __align__(16) u8 lds[3][8192];   // A 4KB + B 4KB per buffer
  int wg = xcd_swz(blockIdx.x, gridDim.x);
  int ntile = wg % 22, mtile = wg / 22;
  int tid = threadIdx.x;
  int w = tid >> 6, l = tid & 63, lr = l & 15, lg = l >> 4;
  int wr = (w >> 1) * 64, wc = (w & 1) * 64;
  int m0 = m_base + mtile * 128;
  int n0 = ntile * 128;
  int rmaxA = m_base + m_count - 1;

  int srow = w * 32 + (l >> 1);      // 128 rows over 4 waves
  int shalf = (l & 1) * 16;
  const u8* a0 = feat8 + (size_t)imin(m0 + srow, rmaxA) * cD + shalf;
  const u8* b0 = attw8 + (size_t)(n0 + srow) * cD + shalf;
  int w1024 = w * 1024;

  int offA[4], offB[4];
#pragma unroll
  for (int mt = 0; mt < 4; ++mt) offA[mt] = (wr + mt * 16 + lr) * 32 + lg * 8;
#pragma unroll
  for (int nt = 0; nt < 4; ++nt) offB[nt] = 4096 + (wc + nt * 16 + lr) * 32 + lg * 8;

  floatx4 acc[4][4];
  floatx4 zero = {0.f, 0.f, 0.f, 0.f};
#pragma unroll
  for (int a = 0; a < 4; ++a)
#pragma unroll
    for (int q = 0; q < 4; ++q) acc[a][q] = zero;

  auto stage = [&](int buf) {
    u8* L = &lds[buf][0];
    gload16(a0, L + w1024);
    gload16(b0, L + 4096 + w1024);
    a0 += 32; b0 += 32;
  };

  stage(0); stage(1);
  int c0 = 0, c1 = 1, c2 = 2;
  constexpr int NK = cD / 32;  // 22
  for (int t = 0; t < NK; ++t) {
    if (t + 1 < NK) PIPE_BAR2(); else PIPE_BAR0();
    if (t + 2 < NK) stage(c2);
    const u8* Lc = lds[c0];
    long av[4], bv[4];
#pragma unroll
    for (int mt = 0; mt < 4; ++mt) av[mt] = *(const long*)(Lc + offA[mt]);
#pragma unroll
    for (int nt = 0; nt < 4; ++nt) bv[nt] = *(const long*)(Lc + offB[nt]);
#pragma unroll
    for (int mt = 0; mt < 4; ++mt)
#pragma unroll
      for (int nt = 0; nt < 4; ++nt)
        acc[mt][nt] = mfma_fp8(av[mt], bv[nt], acc[mt][nt]);
    int tmp = c0; c0 = c1; c1 = c2; c2 = tmp;
  }

  // epilogue: S = acc/1024; exp (pad bias -1e30 -> 0); fp8 scatter; diag zero; partials
  int w1 = w & 1;
  float ab[4]; int kc[4];
#pragma unroll
  for (int nt = 0; nt < 4; ++nt) {
    int k = n0 + wc + nt * 16 + lr;
    kc[nt] = k;
    ab[nt] = (k < cPM1) ? att_b[k] : -1e30f;
  }
#pragma unroll
  for (int mt = 0; mt < 4; ++mt) {
#pragma unroll
    for (int r = 0; r < 4; ++r) {
      int i = m0 + wr + mt * 16 + lg * 4 + r;
      int il = i - pp_base;
      bool rowok = (unsigned)(i - m_base) < (unsigned)m_count;
      int pl = i % cP;
      size_t rowbase = (size_t)il * cNPAD;
      float s = 0.f;
#pragma unroll
      for (int nt = 0; nt < 4; ++nt) {
        int k = kc[nt];
        float e = __expf(acc[mt][nt][r] * kSInv + ab[nt]);
        s += e;
        int j = k + (k >= pl ? 1 : 0);
        if (rowok && j < cNPAD) Pp8[rowbase + j] = f2fp8(e);
        // diagonal slot never hit by the scatter -> zero it exactly once
        if (rowok && (k == pl || (k == cPM1 - 1 && pl == cPM1)))
          Pp8[rowbase + pl] = 0;
      }
      s += __shfl_xor(s, 1); s += __shfl_xor(s, 2);
      s += __shfl_xor(s, 4); s += __shfl_xor(s, 8);
      if (lr == 0 && rowok)
        partial[(size_t)(ntile * 2 + w1) * cM + il] = s;
    }
  }
}

// ---------------- GEMM 2 (fp8, 3-buf): att_feat = (Pp8 @ featT8^T) / (denom*16)
__global__ __launch_bounds__(256, 4) void k_gemm_pv2(
    const u8* __restrict__ Pp8, const u8* __restrict__ featT8,
    const float* __restrict__ denom, ushort_t* __restrict__ af,
    int b_base, int pp_base, int ft_base, int af_base) {
  __shared__ __align__(16) u8 lds[3][8192];
  int wg = xcd_swz(blockIdx.x, gridDim.x);
  int ntile = wg % 6;
  int t6 = wg / 6;
  int mtile = t6 % 22;
  int b = b_base + t6 / 22;
  int tid = threadIdx.x;
  int w = tid >> 6, l = tid & 63, lr = l & 15, lg = l >> 4;
  int wr = (w >> 1) * 64, wc = (w & 1) * 64;
  int m0l = mtile * 128;
  int n0 = ntile * 128;
  int bP = b * cP - pp_base;

  int srow = w * 32 + (l >> 1);
  int shalf = (l & 1) * 16;
  const u8* a0 = Pp8 + (size_t)(bP + imin(m0l + srow, cP - 1)) * cNPAD + shalf;
  const u8* b0 = featT8 + ((size_t)(b - ft_base) * cFTR + n0 + srow) * cNPAD + shalf;
  int w1024 = w * 1024;

  int offA[4], offB[4];
#pragma unroll
  for (int mt = 0; mt < 4; ++mt) offA[mt] = (wr + mt * 16 + lr) * 32 + lg * 8;
#pragma unroll
  for (int nt = 0; nt < 4; ++nt) offB[nt] = 4096 + (wc + nt * 16 + lr) * 32 + lg * 8;

  floatx4 acc[4][4];
  floatx4 zero = {0.f, 0.f, 0.f, 0.f};
#pragma unroll
  for (int a = 0; a < 4; ++a)
#pragma unroll
    for (int q = 0; q < 4; ++q) acc[a][q] = zero;

  auto stage = [&](int buf) {
    u8* L = &lds[buf][0];
    gload16(a0, L + w1024);
    gload16(b0, L + 4096 + w1024);
    a0 += 32; b0 += 32;
  };

  stage(0); stage(1);
  int c0 = 0, c1 = 1, c2 = 2;
  constexpr int NK = cP / 32;  // 87 (pad cols never read)
  for (int t = 0; t < NK; ++t) {
    if (t + 1 < NK) PIPE_BAR2(); else PIPE_BAR0();
    if (t + 2 < NK) stage(c2);
    const u8* Lc = lds[c0];
    long av[4], bv[4];
#pragma unroll
    for (int mt = 0; mt < 4; ++mt) av[mt] = *(const long*)(Lc + offA[mt]);
#pragma unroll
    for (int nt = 0; nt < 4; ++nt) bv[nt] = *(const long*)(Lc + offB[nt]);
#pragma unroll
    for (int mt = 0; mt < 4; ++mt)
#pragma unroll
      for (int nt = 0; nt < 4; ++nt)
        acc[mt][nt] = mfma_fp8(av[mt], bv[nt], acc[mt][nt]);
    int tmp = c0; c0 = c1; c1 = c2; c2 = tmp;
  }

#pragma unroll
  for (int mt = 0; mt < 4; ++mt)
#pragma unroll
    for (int r = 0; r < 4; ++r) {
      int p = m0l + wr + mt * 16 + lg * 4 + r;
      if (p >= cP) continue;
      float dn = denom[bP + p] * kFeatScale;
#pragma unroll
      for (int nt = 0; nt < 4; ++nt) {
        int dd = n0 + wc + nt * 16 + lr;
        if (dd < cD)
          af[((size_t)(b * cP + p) - af_base) * cD + dd] = f2bf(acc[mt][nt][r] / dn);
      }
    }
}

// ---------------- GEMM 3 (bf16, 3-buf A): [att_feat|feat] @ Wt^T + epilogue
__global__ __launch_bounds__(256, 4) void k_gemm_out(
    const ushort_t* __restrict__ af, const ushort_t* __restrict__ feat,
    const ushort_t* __restrict__ Wt,
    const float* __restrict__ reg_b, const float* __restrict__ cls_b,
    const float* __restrict__ anchors,
    float* __restrict__ out0, float* __restrict__ out1,
    float* __restrict__ out2, float* __restrict__ out3,
    int m_base, int m_count, int af_base) {
  __shared__ __align__(16) ushort_t sA[3][4096];
  int tid = threadIdx.x;
  int w = tid >> 6, l = tid & 63, lr = l & 15, lg = l >> 4;
  int wr = w * 32;
  int m0 = m_base + blockIdx.x * 128;
  int lastRow = m_base + m_count - 1;

  int srow = w * 16 + (l >> 2);
  int scol = ((l & 3) * 8) ^ swz8(srow);
  const ushort_t* pa0_af = af + (size_t)(imin(m0 + srow, lastRow) - af_base) * cD + scol;
  const ushort_t* pa1_af = af + (size_t)(imin(m0 + 64 + srow, lastRow) - af_base) * cD + scol;
  const ushort_t* pa0_f  = feat + (size_t)imin(m0 + srow, lastRow) * cD + scol;
  const ushort_t* pa1_f  = feat + (size_t)imin(m0 + 64 + srow, lastRow) * cD + scol;
  int lbase = w * 512;

  int offO[2];
#pragma unroll
  for (int mt = 0; mt < 2; ++mt) {
    int row = wr + mt * 16 + lr;
    offO[mt] = row * 32 + ((lg * 8) ^ swz8(row));
  }

  floatx4 zero = {0.f, 0.f, 0.f, 0.f};
  floatx4 acc[2][5];
#pragma unroll
  for (int a = 0; a < 2; ++a)
#pragma unroll
    for (int q = 0; q < 5; ++q) acc[a][q] = zero;

  auto stageA = [&](int buf, int kk) {
    const ushort_t *s0, *s1;
    if (kk < 22) { s0 = pa0_af + kk * 32; s1 = pa1_af + kk * 32; }
    else         { s0 = pa0_f + (kk - 22) * 32; s1 = pa1_f + (kk - 22) * 32; }
    gload16(s0, &sA[buf][lbase]);
    gload16(s1, &sA[buf][lbase + 2048]);
  };

  stageA(0, 0); stageA(1, 1);
  int c0 = 0, c1 = 1, c2 = 2;
  for (int kk = 0; kk < 44; ++kk) {
    if (kk + 1 < 44) PIPE_BAR2(); else PIPE_BAR0();
    int kb = kk * 32 + lg * 8;
    short8 bvv[5];
#pragma unroll
    for (int nt = 0; nt < 5; ++nt)
      bvv[nt] = *(const short8*)(Wt + (size_t)(nt * 16 + lr) * 1408 + kb);
    if (kk + 2 < 44) stageA(c2, kk + 2);
    short8 avv[2];
#pragma unroll
    for (int mt = 0; mt < 2; ++mt)
      avv[mt] = *(const short8*)&sA[c0][offO[mt]];
#pragma unroll
    for (int nt = 0; nt < 5; ++nt)
#pragma unroll
      for (int mt = 0; mt < 2; ++mt)
        acc[mt][nt] = __builtin_amdgcn_mfma_f32_16x16x32_bf16(avv[mt], bvv[nt], acc[mt][nt], 0, 0, 0);
    int tmp = c0; c0 = c1; c1 = c2; c2 = tmp;
  }

#pragma unroll
  for (int mt = 0; mt < 2; ++mt)
#pragma unroll
    for (int nt = 0; nt < 5; ++nt)
#pragma unroll
      for (int r = 0; r < 4; ++r) {
        int i = m0 + wr + mt * 16 + lg * 4 + r;
        if (i - m_base >= m_count) continue;
        int o = nt * 16 + lr;
        int p = i % cP;
        float v = acc[mt][nt][r];
        const float* an = anchors + (size_t)p * 74;
        if (o == 0)        { out2[i] = an[1] + v + reg_b[0]; out1[i] = an[0]; }
        else if (o < 73)   { out0[(size_t)i * 72 + (o - 1)] = an[1 + o] + v + reg_b[o]; }
        else if (o == 73)  { out3[(size_t)i * 2]     = v + cls_b[0]; }
        else if (o == 74)  { out3[(size_t)i * 2 + 1] = v + cls_b[1]; }
      }
}

extern "C" void kernel_launch(void* const* d_in, const int* in_sizes, int n_in,
                              void* d_out, int out_size, void* d_ws, size_t ws_size,
                              hipStream_t stream) {
  const float* x       = (const float*)d_in[0];
  const float* conv_w  = (const float*)d_in[1];
  const float* conv_b  = (const float*)d_in[2];
  const float* att_w   = (const float*)d_in[3];
  const float* att_b   = (const float*)d_in[4];
  const float* cls_w   = (const float*)d_in[5];
  const float* cls_b   = (const float*)d_in[6];
  const float* reg_w   = (const float*)d_in[7];
  const float* reg_b   = (const float*)d_in[8];
  const float* anchors = (const float*)d_in[9];
  const int*   cut_x   = (const int*)d_in[10];
  const unsigned char* invalid = (const unsigned char*)d_in[11];
  float* out0 = (float*)d_out;
  float* out1 = out0 + (size_t)cM * 72;
  float* out2 = out1 + cM;
  float* out3 = out2 + cM;

  size_t off = 0;
  char* base = (char*)d_ws;
  auto carve = [&](size_t bytes) -> void* {
    void* r = base + off; off += (bytes + 255) & ~(size_t)255; return r;
  };
  float* fbuf    = (float*)carve((size_t)cNB * cAFC * cFH * cFW * 4);
  ushort_t* feat = (ushort_t*)carve((size_t)cM * cD * 2);
  u8* feat8      = (u8*)carve((size_t)cM * cD);
  u8* attw8      = (u8*)carve((size_t)cNPAD * cD);
  ushort_t* Wt   = (ushort_t*)carve((size_t)80 * 1408 * 2);
  float* partial = (float*)carve((size_t)44 * cM * 4);
  float* denom   = (float*)carve((size_t)cM * 4);

  size_t featT_full = (size_t)cNB * cFTR * cNPAD, featT_one = (size_t)cFTR * cNPAD;
  size_t af_full    = (size_t)cM * cD * 2,        af_one    = (size_t)cP * cD * 2;
  size_t pp_full    = (size_t)cM * cNPAD,         pp_one    = (size_t)cNPAD * cNPAD;

  size_t needA = off + featT_full + af_full + pp_full;
  size_t needB = off + featT_full + af_full + pp_one;
  int mode = (ws_size >= needA) ? 0 : ((ws_size >= needB) ? 1 : 2);

  u8 *featT8, *Pp8; ushort_t *af;
  if (mode == 0)      { featT8 = (u8*)carve(featT_full); af = (ushort_t*)carve(af_full); Pp8 = (u8*)carve(pp_full); }
  else if (mode == 1) { featT8 = (u8*)carve(featT_full); af = (ushort_t*)carve(af_full); Pp8 = (u8*)carve(pp_one); }
  else                { featT8 = (u8*)carve(featT_one);  af = (ushort_t*)carve(af_one);  Pp8 = (u8*)carve(pp_one); }

  k_conv4<<<(cNB * 16 * 220 + 255) / 256, 256, 0, stream>>>(x, conv_w, conv_b, fbuf);
  k_prep_w<<<(cNPAD * cD + 80 * 1408 + 255) / 256, 256, 0, stream>>>(att_w, reg_w, cls_w, attw8, Wt);

  if (mode == 0) {
    k_gatherT<<<dim3(44, 11, 8), 256, 0, stream>>>(fbuf, cut_x, invalid, feat, feat8, featT8, 0);
    k_gemm_s2<<<174 * 22, 256, 0, stream>>>(feat8, attw8, att_b, Pp8, partial, 0, cM, 0);
    k_denom<<<(cM + 255) / 256, 256, 0, stream>>>(partial, denom, cM);
    k_gemm_pv2<<<8 * 22 * 6, 256, 0, stream>>>(Pp8, featT8, denom, af, 0, 0, 0, 0);
    k_gemm_out<<<174, 256, 0, stream>>>(af, feat, Wt, reg_b, cls_b, anchors,
                                        out0, out1, out2, out3, 0, cM, 0);
  } else if (mode == 1) {
    k_gatherT<<<dim3(44, 11, 8), 256, 0, stream>>>(fbuf, cut_x, invalid, feat, feat8, featT8, 0);
    for (int b = 0; b < cNB; ++b) {
      k_gemm_s2<<<22 * 22, 256, 0, stream>>>(feat8, attw8, att_b, Pp8, partial, b * cP, cP, b * cP);
      k_denom<<<(cP + 255) / 256, 256, 0, stream>>>(partial, denom, cP);
      k_gemm_pv2<<<22 * 6, 256, 0, stream>>>(Pp8, featT8, denom, af, b, b * cP, 0, 0);
    }
    k_gemm_out<<<174, 256, 0, stream>>>(af, feat, Wt, reg_b, cls_b, anchors,
                                        out0, out1, out2, out3, 0, cM, 0);
  } else {
    for (int b = 0; b < cNB; ++b) {
      k_gatherT<<<dim3(44, 11, 1), 256, 0, stream>>>(fbuf, cut_x, invalid, feat, feat8, featT8, b);
      k_gemm_s2<<<22 * 22, 256, 0, stream>>>(feat8, attw8, att_b, Pp8, partial, b * cP, cP, b * cP);
      k_denom<<<(cP + 255) / 256, 256, 0, stream>>>(partial, denom, cP);
      k_gemm_pv2<<<22 * 6, 256, 0, stream>>>(Pp8, featT8, denom, af, b, b * cP, b, b * cP);
      k_gemm_out<<<22, 256, 0, stream>>>(af, feat, Wt, reg_b, cls_b, anchors,
                                         out0, out1, out2, out3, b * cP, cP, b * cP);
    }
  }
}

// Round 13
// 321.030 us; speedup vs baseline: 1.5831x; 1.1975x over previous
//
#include <hip/hip_runtime.h>
#include <stdint.h>

typedef short short8 __attribute__((ext_vector_type(8)));
typedef float floatx4 __attribute__((ext_vector_type(4)));
typedef unsigned short ushort_t;
typedef unsigned char u8;

constexpr int cFH = 11, cFW = 20, cP = 2784, cPM1 = 2783, cD = 704;
constexpr int cAFC = 64, cBBC = 512, cNB = 8, cNPAD = 2816, cM = 22272;
constexpr int cFTR = 768;   // featT padded rows
constexpr int cK16_704  = 704 * 16;    // 11264: rowblock stride, K=704
constexpr int cK16_2816 = 2816 * 16;   // 45056: rowblock stride, K=2816
constexpr size_t cFTbatch = (size_t)(cFTR / 16) * cK16_2816;  // per-batch featT8 bytes

static __device__ __forceinline__ float bf2f(unsigned short u) {
  union { unsigned u32; float f; } v; v.u32 = ((unsigned)u) << 16; return v.f;
}
static __device__ __forceinline__ unsigned short f2bf(float f) {
  union { float f; unsigned u; } v; v.f = f;
  unsigned r = v.u + 0x7fffu + ((v.u >> 16) & 1u);
  return (unsigned short)(r >> 16);
}
// float -> OCP e4m3 (RNE + saturation in HW)
static __device__ __forceinline__ u8 f2fp8(float f) {
  int v = __builtin_amdgcn_cvt_pk_fp8_f32(f, 0.f, 0, false);
  return (u8)(v & 0xff);
}
static __device__ __forceinline__ int imin(int a, int b) { return a < b ? a : b; }
// bf16 LDS XOR swizzle (kept for gemm_out)
static __device__ __forceinline__ int swz8(int row) { return ((row >> 1) & 3) << 3; }

// MFMA-ready tiled layout: 512B block = 16 rows x 32 k-bytes,
// internal order [kchunk(4)][row(16)][8B]. k16 = K*16 bytes per rowblock.
static __device__ __forceinline__ size_t tiled_addr(int R, int c, int k16) {
  return (size_t)(R >> 4) * k16 + (size_t)(((c >> 5) << 9) + (((c >> 3) & 3) << 7) +
         ((R & 15) << 3) + (c & 7));
}

// bijective XCD-chunk swizzle (m204)
static __device__ __forceinline__ int xcd_swz(int orig, int total) {
  int q = total >> 3, r = total & 7;
  int xcd = orig & 7, pos = orig >> 3;
  return (xcd < r ? xcd * (q + 1) : r * (q + 1) + (xcd - r) * q) + pos;
}

// async global->LDS, 16B per lane, wave-uniform LDS base + lane*16
static __device__ __forceinline__ void gload16(const void* g, void* l) {
  __builtin_amdgcn_global_load_lds(
      (const __attribute__((address_space(1))) unsigned int*)g,
      (__attribute__((address_space(3))) unsigned int*)l, 16, 0, 0);
}

static __device__ __forceinline__ floatx4 mfma_fp8(long a, long b, floatx4 c) {
  return __builtin_amdgcn_mfma_f32_16x16x32_fp8_fp8(a, b, c, 0, 0, 0);
}

#define PIPE_BAR2() asm volatile("s_waitcnt vmcnt(2)\n\ts_barrier" ::: "memory")
#define PIPE_BAR0() asm volatile("s_waitcnt vmcnt(0)\n\ts_barrier" ::: "memory")

constexpr float kFeatScale = 16.f;   // feat8 = feat * 16
constexpr float kAttwScale = 64.f;   // attw8 = att_w * 64
constexpr float kSInv = 1.f / (kFeatScale * kAttwScale);

// ---------------- 1x1 conv, 4 output channels per thread
__global__ void k_conv4(const float* __restrict__ x, const float* __restrict__ w,
                        const float* __restrict__ bias, float* __restrict__ f) {
  int idx = blockIdx.x * 256 + threadIdx.x;
  if (idx >= cNB * 16 * 220) return;
  int yx = idx % 220;
  int og = (idx / 220) % 16;
  int b  = idx / (220 * 16);
  int o0 = og * 4;
  const float* xp = x + (size_t)b * cBBC * 220 + yx;
  const float* w0 = w + (size_t)o0 * cBBC;
  const float* w1 = w0 + cBBC;
  const float* w2 = w1 + cBBC;
  const float* w3 = w2 + cBBC;
  float a0 = 0.f, a1 = 0.f, a2 = 0.f, a3 = 0.f;
#pragma unroll 4
  for (int c = 0; c < cBBC; ++c) {
    float xv = xp[(size_t)c * 220];
    a0 += xv * w0[c]; a1 += xv * w1[c]; a2 += xv * w2[c]; a3 += xv * w3[c];
  }
  f[((size_t)(b * cAFC + o0) * 220) + yx]     = a0 + bias[o0];
  f[((size_t)(b * cAFC + o0 + 1) * 220) + yx] = a1 + bias[o0 + 1];
  f[((size_t)(b * cAFC + o0 + 2) * 220) + yx] = a2 + bias[o0 + 2];
  f[((size_t)(b * cAFC + o0 + 3) * 220) + yx] = a3 + bias[o0 + 3];
}

// ---------------- fused gather + transpose: feat bf16 linear, feat8/featT8 fp8 TILED
__global__ void k_gatherT(const float* __restrict__ f, const int* __restrict__ cut_x,
                          const unsigned char* __restrict__ invalid,
                          ushort_t* __restrict__ feat, u8* __restrict__ feat8,
                          u8* __restrict__ featT8, int b_base) {
  __shared__ ushort_t tile[64][66];
  int bz = blockIdx.z;
  int b  = b_base + bz;
  int p0 = blockIdx.x * 64, d0 = blockIdx.y * 64;
  int t = threadIdx.x;
#pragma unroll
  for (int m = 0; m < 16; ++m) {
    int idx = t + m * 256; int r = idx >> 6, c = idx & 63;
    int p = p0 + r, d = d0 + c;
    ushort_t v = 0;
    if (p < cP) {
      int o = d / cFH, i2 = d - o * cFH;
      int cx = cut_x[p * cFH + i2];
      float vv = invalid[p * cFH + i2] ? 0.f
               : f[((size_t)(b * cAFC + o) * cFH + i2) * cFW + cx];
      v = f2bf(vv);
      feat[((size_t)b * cP + p) * cD + d] = v;
      feat8[tiled_addr(b * cP + p, d, cK16_704)] = f2fp8(vv * kFeatScale);
    }
    tile[r][c] = v;
  }
  __syncthreads();
#pragma unroll
  for (int m = 0; m < 16; ++m) {
    int idx = t + m * 256; int r = idx >> 6, c = idx & 63;
    float tv = bf2f(tile[c][r]);
    featT8[(size_t)bz * cFTbatch + tiled_addr(d0 + r, p0 + c, cK16_2816)] =
        f2fp8(tv * kFeatScale);
  }
}

// ---------------- att_w -> fp8 (x64) TILED [2816][704]  +  Wt bf16 [80][1408]
__global__ void k_prep_w(const float* __restrict__ att_w, const float* __restrict__ reg_w,
                         const float* __restrict__ cls_w,
                         u8* __restrict__ attw8, ushort_t* __restrict__ Wt) {
  int idx = blockIdx.x * 256 + threadIdx.x;
  constexpr int n1 = cNPAD * cD;
  if (idx < n1) {
    int r = idx / cD, k = idx % cD;
    attw8[tiled_addr(r, k, cK16_704)] = (r < cPM1) ? f2fp8(att_w[idx] * kAttwScale) : (u8)0;
  } else {
    int j = idx - n1;
    if (j < 80 * 1408) {
      int r = j / 1408, k = j % 1408;
      float v = 0.f;
      if (r < 73) v = reg_w[(size_t)r * 1408 + k];
      else if (r < 75) v = cls_w[(size_t)(r - 73) * 1408 + k];
      Wt[j] = f2bf(v);
    }
  }
}

// ---------------- denom[i] = sum of 44 partial slots
__global__ void k_denom(const float* __restrict__ partial, float* __restrict__ denom, int n) {
  int i = blockIdx.x * 256 + threadIdx.x;
  if (i >= n) return;
  float s = 0.f;
#pragma unroll 4
  for (int q = 0; q < 44; ++q) s += partial[(size_t)q * cM + i];
  denom[i] = s;
}

// ---------------- GEMM 1 (fp8 tiled, 3-buf): S = feat8 @ attw8^T; exp; scatter+diag; partials
__global__ __launch_bounds__(256, 4) void k_gemm_s2(
    const u8* __restrict__ feat8, const u8* __restrict__ attw8,
    const float* __restrict__ att_b, u8* __restrict__ Pp8,
    float* __restrict__ partial, int m_base, int m_count, int pp_base) {
  __shared__ __align__(16) u8 lds[3][8192];   // A 4KB + B 4KB per buffer
  int wg = xcd_swz(blockIdx.x, gridDim.x);
  int ntile = wg % 22, mtile = wg / 22;
  int tid = threadIdx.x;
  int w = tid >> 6, l = tid & 63, lr = l & 15, lg = l >> 4;
  int wr = (w >> 1) * 64, wc = (w & 1) * 64;
  int m0 = m_base + mtile * 128;
  int n0 = ntile * 128;

  // staging: slot q = w*64+l holds 16B at tiled position; source is contiguous
  int q = w * 64 + l;
  int rbq = q >> 5, sq = (q & 31) * 16;
  int rbA = imin((m0 >> 4) + rbq, (cM >> 4) - 1);
  const u8* a0 = feat8 + (size_t)rbA * cK16_704 + sq;
  const u8* b0 = attw8 + (size_t)((n0 >> 4) + rbq) * cK16_704 + sq;
  int w1024 = w * 1024;

  int offA[4], offB[4];
#pragma unroll
  for (int mt = 0; mt < 4; ++mt) offA[mt] = ((wr >> 4) + mt) * 512 + lg * 128 + lr * 8;
#pragma unroll
  for (int nt = 0; nt < 4; ++nt) offB[nt] = 4096 + ((wc >> 4) + nt) * 512 + lg * 128 + lr * 8;

  floatx4 acc[4][4];
  floatx4 zero = {0.f, 0.f, 0.f, 0.f};
#pragma unroll
  for (int a = 0; a < 4; ++a)
#pragma unroll
    for (int qq = 0; qq < 4; ++qq) acc[a][qq] = zero;

  auto stage = [&](int buf) {
    u8* L = &lds[buf][0];
    gload16(a0, L + w1024);
    gload16(b0, L + 4096 + w1024);
    a0 += 512; b0 += 512;
  };

  stage(0); stage(1);
  int c0 = 0, c1 = 1, c2 = 2;
  constexpr int NK = cD / 32;  // 22
  for (int t = 0; t < NK; ++t) {
    if (t + 1 < NK) PIPE_BAR2(); else PIPE_BAR0();
    if (t + 2 < NK) stage(c2);
    const u8* Lc = lds[c0];
    long av[4], bv[4];
#pragma unroll
    for (int mt = 0; mt < 4; ++mt) av[mt] = *(const long*)(Lc + offA[mt]);
#pragma unroll
    for (int nt = 0; nt < 4; ++nt) bv[nt] = *(const long*)(Lc + offB[nt]);
#pragma unroll
    for (int mt = 0; mt < 4; ++mt)
#pragma unroll
      for (int nt = 0; nt < 4; ++nt)
        acc[mt][nt] = mfma_fp8(av[mt], bv[nt], acc[mt][nt]);
    int tmp = c0; c0 = c1; c1 = c2; c2 = tmp;
  }

  // epilogue: S = acc/1024; exp (pad bias -1e30 -> 0); fp8 tiled scatter; diag zero; partials
  int w1 = w & 1;
  float ab[4]; int kc[4];
#pragma unroll
  for (int nt = 0; nt < 4; ++nt) {
    int k = n0 + wc + nt * 16 + lr;
    kc[nt] = k;
    ab[nt] = (k < cPM1) ? att_b[k] : -1e30f;
  }
#pragma unroll
  for (int mt = 0; mt < 4; ++mt) {
#pragma unroll
    for (int r = 0; r < 4; ++r) {
      int i = m0 + wr + mt * 16 + lg * 4 + r;
      int il = i - pp_base;
      bool rowok = (unsigned)(i - m_base) < (unsigned)m_count;
      int pl = i % cP;
      float s = 0.f;
#pragma unroll
      for (int nt = 0; nt < 4; ++nt) {
        int k = kc[nt];
        float e = __expf(acc[mt][nt][r] * kSInv + ab[nt]);
        s += e;
        int j = k + (k >= pl ? 1 : 0);
        if (rowok && j < cNPAD) Pp8[tiled_addr(il, j, cK16_2816)] = f2fp8(e);
        // diagonal slot never hit by the scatter -> zero it exactly once
        if (rowok && (k == pl || (k == cPM1 - 1 && pl == cPM1)))
          Pp8[tiled_addr(il, pl, cK16_2816)] = 0;
      }
      s += __shfl_xor(s, 1); s += __shfl_xor(s, 2);
      s += __shfl_xor(s, 4); s += __shfl_xor(s, 8);
      if (lr == 0 && rowok)
        partial[(size_t)(ntile * 2 + w1) * cM + il] = s;
    }
  }
}

// ---------------- GEMM 2 (fp8 tiled, 3-buf): att_feat = (Pp8 @ featT8^T) / (denom*16)
__global__ __launch_bounds__(256, 4) void k_gemm_pv2(
    const u8* __restrict__ Pp8, const u8* __restrict__ featT8,
    const float* __restrict__ denom, ushort_t* __restrict__ af,
    int b_base, int pp_base, int ft_base, int af_base, int rbMaxPp) {
  __shared__ __align__(16) u8 lds[3][8192];
  int wg = xcd_swz(blockIdx.x, gridDim.x);
  int ntile = wg % 6;
  int t6 = wg / 6;
  int mtile = t6 % 22;
  int b = b_base + t6 / 22;
  int tid = threadIdx.x;
  int w = tid >> 6, l = tid & 63, lr = l & 15, lg = l >> 4;
  int wr = (w >> 1) * 64, wc = (w & 1) * 64;
  int m0l = mtile * 128;
  int n0 = ntile * 128;
  int bP = b * cP - pp_base;

  int q = w * 64 + l;
  int rbq = q >> 5, sq = (q & 31) * 16;
  int rbA = imin(((bP + m0l) >> 4) + rbq, rbMaxPp);
  const u8* a0 = Pp8 + (size_t)rbA * cK16_2816 + sq;
  const u8* b0 = featT8 + (size_t)(b - ft_base) * cFTbatch
               + (size_t)((n0 >> 4) + rbq) * cK16_2816 + sq;
  int w1024 = w * 1024;

  int offA[4], offB[4];
#pragma unroll
  for (int mt = 0; mt < 4; ++mt) offA[mt] = ((wr >> 4) + mt) * 512 + lg * 128 + lr * 8;
#pragma unroll
  for (int nt = 0; nt < 4; ++nt) offB[nt] = 4096 + ((wc >> 4) + nt) * 512 + lg * 128 + lr * 8;

  floatx4 acc[4][4];
  floatx4 zero = {0.f, 0.f, 0.f, 0.f};
#pragma unroll
  for (int a = 0; a < 4; ++a)
#pragma unroll
    for (int qq = 0; qq < 4; ++qq) acc[a][qq] = zero;

  auto stage = [&](int buf) {
    u8* L = &lds[buf][0];
    gload16(a0, L + w1024);
    gload16(b0, L + 4096 + w1024);
    a0 += 512; b0 += 512;
  };

  stage(0); stage(1);
  int c0 = 0, c1 = 1, c2 = 2;
  constexpr int NK = cP / 32;  // 87 (pad kblock 87 never staged)
  for (int t = 0; t < NK; ++t) {
    if (t + 1 < NK) PIPE_BAR2(); else PIPE_BAR0();
    if (t + 2 < NK) stage(c2);
    const u8* Lc = lds[c0];
    long av[4], bv[4];
#pragma unroll
    for (int mt = 0; mt < 4; ++mt) av[mt] = *(const long*)(Lc + offA[mt]);
#pragma unroll
    for (int nt = 0; nt < 4; ++nt) bv[nt] = *(const long*)(Lc + offB[nt]);
#pragma unroll
    for (int mt = 0; mt < 4; ++mt)
#pragma unroll
      for (int nt = 0; nt < 4; ++nt)
        acc[mt][nt] = mfma_fp8(av[mt], bv[nt], acc[mt][nt]);
    int tmp = c0; c0 = c1; c1 = c2; c2 = tmp;
  }

#pragma unroll
  for (int mt = 0; mt < 4; ++mt)
#pragma unroll
    for (int r = 0; r < 4; ++r) {
      int p = m0l + wr + mt * 16 + lg * 4 + r;
      if (p >= cP) continue;
      float dn = denom[bP + p] * kFeatScale;
#pragma unroll
      for (int nt = 0; nt < 4; ++nt) {
        int dd = n0 + wc + nt * 16 + lr;
        if (dd < cD)
          af[((size_t)(b * cP + p) - af_base) * cD + dd] = f2bf(acc[mt][nt][r] / dn);
      }
    }
}

// ---------------- GEMM 3 (bf16, 3-buf A): [att_feat|feat] @ Wt^T + epilogue
__global__ __launch_bounds__(256, 4) void k_gemm_out(
    const ushort_t* __restrict__ af, const ushort_t* __restrict__ feat,
    const ushort_t* __restrict__ Wt,
    const float* __restrict__ reg_b, const float* __restrict__ cls_b,
    const float* __restrict__ anchors,
    float* __restrict__ out0, float* __restrict__ out1,
    float* __restrict__ out2, float* __restrict__ out3,
    int m_base, int m_count, int af_base) {
  __shared__ __align__(16) ushort_t sA[3][4096];
  int tid = threadIdx.x;
  int w = tid >> 6, l = tid & 63, lr = l & 15, lg = l >> 4;
  int wr = w * 32;
  int m0 = m_base + blockIdx.x * 128;
  int lastRow = m_base + m_count - 1;

  int srow = w * 16 + (l >> 2);
  int scol = ((l & 3) * 8) ^ swz8(srow);
  const ushort_t* pa0_af = af + (size_t)(imin(m0 + srow, lastRow) - af_base) * cD + scol;
  const ushort_t* pa1_af = af + (size_t)(imin(m0 + 64 + srow, lastRow) - af_base) * cD + scol;
  const ushort_t* pa0_f  = feat + (size_t)imin(m0 + srow, lastRow) * cD + scol;
  const ushort_t* pa1_f  = feat + (size_t)imin(m0 + 64 + srow, lastRow) * cD + scol;
  int lbase = w * 512;

  int offO[2];
#pragma unroll
  for (int mt = 0; mt < 2; ++mt) {
    int row = wr + mt * 16 + lr;
    offO[mt] = row * 32 + ((lg * 8) ^ swz8(row));
  }

  floatx4 zero = {0.f, 0.f, 0.f, 0.f};
  floatx4 acc[2][5];
#pragma unroll
  for (int a = 0; a < 2; ++a)
#pragma unroll
    for (int q = 0; q < 5; ++q) acc[a][q] = zero;

  auto stageA = [&](int buf, int kk) {
    const ushort_t *s0, *s1;
    if (kk < 22) { s0 = pa0_af + kk * 32; s1 = pa1_af + kk * 32; }
    else         { s0 = pa0_f + (kk - 22) * 32; s1 = pa1_f + (kk - 22) * 32; }
    gload16(s0, &sA[buf][lbase]);
    gload16(s1, &sA[buf][lbase + 2048]);
  };

  stageA(0, 0); stageA(1, 1);
  int c0 = 0, c1 = 1, c2 = 2;
  for (int kk = 0; kk < 44; ++kk) {
    if (kk + 1 < 44) PIPE_BAR2(); else PIPE_BAR0();
    int kb = kk * 32 + lg * 8;
    short8 bvv[5];
#pragma unroll
    for (int nt = 0; nt < 5; ++nt)
      bvv[nt] = *(const short8*)(Wt + (size_t)(nt * 16 + lr) * 1408 + kb);
    if (kk + 2 < 44) stageA(c2, kk + 2);
    short8 avv[2];
#pragma unroll
    for (int mt = 0; mt < 2; ++mt)
      avv[mt] = *(const short8*)&sA[c0][offO[mt]];
#pragma unroll
    for (int nt = 0; nt < 5; ++nt)
#pragma unroll
      for (int mt = 0; mt < 2; ++mt)
        acc[mt][nt] = __builtin_amdgcn_mfma_f32_16x16x32_bf16(avv[mt], bvv[nt], acc[mt][nt], 0, 0, 0);
    int tmp = c0; c0 = c1; c1 = c2; c2 = tmp;
  }

#pragma unroll
  for (int mt = 0; mt < 2; ++mt)
#pragma unroll
    for (int nt = 0; nt < 5; ++nt)
#pragma unroll
      for (int r = 0; r < 4; ++r) {
        int i = m0 + wr + mt * 16 + lg * 4 + r;
        if (i - m_base >= m_count) continue;
        int o = nt * 16 + lr;
        int p = i % cP;
        float v = acc[mt][nt][r];
        const float* an = anchors + (size_t)p * 74;
        if (o == 0)        { out2[i] = an[1] + v + reg_b[0]; out1[i] = an[0]; }
        else if (o < 73)   { out0[(size_t)i * 72 + (o - 1)] = an[1 + o] + v + reg_b[o]; }
        else if (o == 73)  { out3[(size_t)i * 2]     = v + cls_b[0]; }
        else if (o == 74)  { out3[(size_t)i * 2 + 1] = v + cls_b[1]; }
      }
}

extern "C" void kernel_launch(void* const* d_in, const int* in_sizes, int n_in,
                              void* d_out, int out_size, void* d_ws, size_t ws_size,
                              hipStream_t stream) {
  const float* x       = (const float*)d_in[0];
  const float* conv_w  = (const float*)d_in[1];
  const float* conv_b  = (const float*)d_in[2];
  const float* att_w   = (const float*)d_in[3];
  const float* att_b   = (const float*)d_in[4];
  const float* cls_w   = (const float*)d_in[5];
  const float* cls_b   = (const float*)d_in[6];
  const float* reg_w   = (const float*)d_in[7];
  const float* reg_b   = (const float*)d_in[8];
  const float* anchors = (const float*)d_in[9];
  const int*   cut_x   = (const int*)d_in[10];
  const unsigned char* invalid = (const unsigned char*)d_in[11];
  float* out0 = (float*)d_out;
  float* out1 = out0 + (size_t)cM * 72;
  float* out2 = out1 + cM;
  float* out3 = out2 + cM;

  size_t off = 0;
  char* base = (char*)d_ws;
  auto carve = [&](size_t bytes) -> void* {
    void* r = base + off; off += (bytes + 255) & ~(size_t)255; return r;
  };
  float* fbuf    = (float*)carve((size_t)cNB * cAFC * cFH * cFW * 4);
  ushort_t* feat = (ushort_t*)carve((size_t)cM * cD * 2);
  u8* feat8      = (u8*)carve((size_t)cM * cD);
  u8* attw8      = (u8*)carve((size_t)cNPAD * cD);
  ushort_t* Wt   = (ushort_t*)carve((size_t)80 * 1408 * 2);
  float* partial = (float*)carve((size_t)44 * cM * 4);
  float* denom   = (float*)carve((size_t)cM * 4);

  size_t featT_full = (size_t)cNB * cFTR * cNPAD, featT_one = (size_t)cFTR * cNPAD;
  size_t af_full    = (size_t)cM * cD * 2,        af_one    = (size_t)cP * cD * 2;
  size_t pp_full    = (size_t)cM * cNPAD,         pp_one    = (size_t)cNPAD * cNPAD;

  size_t needA = off + featT_full + af_full + pp_full;
  size_t needB = off + featT_full + af_full + pp_one;
  int mode = (ws_size >= needA) ? 0 : ((ws_size >= needB) ? 1 : 2);

  u8 *featT8, *Pp8; ushort_t *af;
  if (mode == 0)      { featT8 = (u8*)carve(featT_full); af = (ushort_t*)carve(af_full); Pp8 = (u8*)carve(pp_full); }
  else if (mode == 1) { featT8 = (u8*)carve(featT_full); af = (ushort_t*)carve(af_full); Pp8 = (u8*)carve(pp_one); }
  else                { featT8 = (u8*)carve(featT_one);  af = (ushort_t*)carve(af_one);  Pp8 = (u8*)carve(pp_one); }

  int rbMaxPp = (mode == 0) ? (cM >> 4) - 1 : (cNPAD >> 4) - 1;

  k_conv4<<<(cNB * 16 * 220 + 255) / 256, 256, 0, stream>>>(x, conv_w, conv_b, fbuf);
  k_prep_w<<<(cNPAD * cD + 80 * 1408 + 255) / 256, 256, 0, stream>>>(att_w, reg_w, cls_w, attw8, Wt);

  if (mode == 0) {
    k_gatherT<<<dim3(44, 11, 8), 256, 0, stream>>>(fbuf, cut_x, invalid, feat, feat8, featT8, 0);
    k_gemm_s2<<<174 * 22, 256, 0, stream>>>(feat8, attw8, att_b, Pp8, partial, 0, cM, 0);
    k_denom<<<(cM + 255) / 256, 256, 0, stream>>>(partial, denom, cM);
    k_gemm_pv2<<<8 * 22 * 6, 256, 0, stream>>>(Pp8, featT8, denom, af, 0, 0, 0, 0, rbMaxPp);
    k_gemm_out<<<174, 256, 0, stream>>>(af, feat, Wt, reg_b, cls_b, anchors,
                                        out0, out1, out2, out3, 0, cM, 0);
  } else if (mode == 1) {
    k_gatherT<<<dim3(44, 11, 8), 256, 0, stream>>>(fbuf, cut_x, invalid, feat, feat8, featT8, 0);
    for (int b = 0; b < cNB; ++b) {
      k_gemm_s2<<<22 * 22, 256, 0, stream>>>(feat8, attw8, att_b, Pp8, partial, b * cP, cP, b * cP);
      k_denom<<<(cP + 255) / 256, 256, 0, stream>>>(partial, denom, cP);
      k_gemm_pv2<<<22 * 6, 256, 0, stream>>>(Pp8, featT8, denom, af, b, b * cP, 0, 0, rbMaxPp);
    }
    k_gemm_out<<<174, 256, 0, stream>>>(af, feat, Wt, reg_b, cls_b, anchors,
                                        out0, out1, out2, out3, 0, cM, 0);
  } else {
    for (int b = 0; b < cNB; ++b) {
      k_gatherT<<<dim3(44, 11, 1), 256, 0, stream>>>(fbuf, cut_x, invalid, feat, feat8, featT8, b);
      k_gemm_s2<<<22 * 22, 256, 0, stream>>>(feat8, attw8, att_b, Pp8, partial, b * cP, cP, b * cP);
      k_denom<<<(cP + 255) / 256, 256, 0, stream>>>(partial, denom, cP);
      k_gemm_pv2<<<22 * 6, 256, 0, stream>>>(Pp8, featT8, denom, af, b, b * cP, b, b * cP, rbMaxPp);
      k_gemm_out<<<22, 256, 0, stream>>>(af, feat, Wt, reg_b, cls_b, anchors,
                                         out0, out1, out2, out3, b * cP, cP, b * cP);
    }
  }
}